// Round 1
// baseline (1232.270 us; speedup 1.0000x reference)
//
#include <hip/hip_runtime.h>

#define B_    8
#define N_    16384
#define K_    16
#define G_    4
#define CQ_   64
#define CV_   64
#define CQG_  16
#define CVG_  16
#define CLPE_ 16
#define NT_   (B_*G_*N_)   // 524288 threads, one per (b,g,n)

typedef float f4v __attribute__((ext_vector_type(4)));

static __device__ __forceinline__ void nt_store4(float* p, float a, float b,
                                                 float c, float d) {
    f4v v = {a, b, c, d};
    __builtin_nontemporal_store(v, (f4v*)p);
}
static __device__ __forceinline__ void nt_store1(float* p, float a) {
    __builtin_nontemporal_store(a, p);
}

// ---------------------------------------------------------------------------
// Kernel 1: LDS-tiled transpose of query/value from channel-major (b,64,n) to
// point-major slabs (bg, n, 16ch); packs xyz into float4; zeroes cent.
// 64 points per block, one bg per block. Reads: 256B-coalesced per wave-instr.
// Writes: 1KB contiguous per wave (full lines). LDS stride 68 -> 2-way max
// bank aliasing (free on CDNA4).
// ---------------------------------------------------------------------------
__global__ __launch_bounds__(256) void gtl_prep(
    const float* __restrict__ query,
    const float* __restrict__ value,
    const float* __restrict__ xyz,
    float4* __restrict__ qT4,
    float4* __restrict__ vT4,
    float4* __restrict__ xyz4,
    float*  __restrict__ cent)
{
    __shared__ float sq[CQG_][68];
    __shared__ float sv[CVG_][68];

    const int t    = threadIdx.x;
    const int bg   = blockIdx.x >> 8;        // 256 tiles of 64 points per bg
    const int tile = blockIdx.x & 255;
    const int n0   = tile << 6;
    const int g    = bg & (G_ - 1);
    const int b    = bg >> 2;

    const int row = t >> 6;    // 0..3 (wave id)
    const int col = t & 63;

    const float* qb = query + (size_t)b*CQ_*N_ + (size_t)g*CQG_*N_ + n0;
    const float* vb = value + (size_t)b*CV_*N_ + (size_t)g*CVG_*N_ + n0;

    #pragma unroll
    for (int cc = 0; cc < 4; ++cc) {
        const int c = (cc << 2) + row;
        sq[c][col] = qb[(size_t)c*N_ + col];
        sv[c][col] = vb[(size_t)c*N_ + col];
    }

    if (t < 64) {
        cent[(size_t)bg*N_ + n0 + t] = 0.f;
        if (g == 0) {
            const size_t pp = (size_t)b*N_ + n0 + t;
            xyz4[pp] = make_float4(xyz[pp*3+0], xyz[pp*3+1], xyz[pp*3+2], 0.f);
        }
    }

    __syncthreads();

    const int p    = t >> 2;   // 0..63
    const int quad = t & 3;    // 0..3
    const int cb   = quad << 2;
    const float4 oq = make_float4(sq[cb+0][p], sq[cb+1][p], sq[cb+2][p], sq[cb+3][p]);
    const float4 ov = make_float4(sv[cb+0][p], sv[cb+1][p], sv[cb+2][p], sv[cb+3][p]);
    const size_t o = ((size_t)bg*N_ + n0 + p)*4 + quad;   // float4 index
    qT4[o] = oq;
    vT4[o] = ov;
}

// ---------------------------------------------------------------------------
// Kernel 2: main fused pass. One thread per (b,g,n).
// XCD-chunked swizzle: 2048 blocks, blockIdx%8 = XCD (round-robin dispatch);
// each XCD owns bgs {4x..4x+3} (same b -> shared xyz4 slab), tiles in order.
// Per-XCD hot set = qT(1MB)+vT(1MB)+xyz4(0.25MB) per bg -> fits 4MB L2.
// fenc/out stores are non-temporal so the 600MB output stream doesn't evict
// the gather slabs.
// ---------------------------------------------------------------------------
__global__ __launch_bounds__(256) void gtl_main(
    const float*  __restrict__ qT,
    const float*  __restrict__ vT,
    const float4* __restrict__ xyz4,
    const int*    __restrict__ nidx,
    const float*  __restrict__ lpeW,
    const float*  __restrict__ lpeB,
    const float*  __restrict__ bnG,
    const float*  __restrict__ bnB,
    const float*  __restrict__ bnM,
    const float*  __restrict__ bnV,
    float* __restrict__ out,
    float* __restrict__ fenc,
    float* __restrict__ cent)
{
    // Folded LPE+BN weights:
    __shared__ float4 sA[CLPE_];  // scale*(center xyz coeffs), w = shift
    __shared__ float4 sB[CLPE_];  // scale*(neighbor xyz coeffs), w = scale*w0

    const int t = threadIdx.x;
    if (t < CLPE_) {
        const float scale = bnG[t] * rsqrtf(bnV[t] + 1e-5f);
        const float shift = (lpeB[t] - bnM[t]) * scale + bnB[t];
        const float w0 = lpeW[t*10+0];
        const float w1 = lpeW[t*10+1], w2 = lpeW[t*10+2], w3 = lpeW[t*10+3];
        const float w4 = lpeW[t*10+4], w5 = lpeW[t*10+5], w6 = lpeW[t*10+6];
        const float w7 = lpeW[t*10+7], w8 = lpeW[t*10+8], w9 = lpeW[t*10+9];
        sA[t] = make_float4(scale*(w1+w4), scale*(w2+w5), scale*(w3+w6), shift);
        sB[t] = make_float4(scale*(w7-w1), scale*(w8-w2), scale*(w9-w3), scale*w0);
    }
    __syncthreads();

    // XCD-chunked work mapping (2048 blocks = 8 XCDs x 256 slots)
    const int wid  = blockIdx.x;
    const int xcd  = wid & 7;
    const int slot = wid >> 3;                 // 0..255 per XCD
    const int bg   = (xcd << 2) | (slot >> 6); // 4 bgs per XCD, same b
    const int n    = ((slot & 63) << 8) | t;   // 64 tiles x 256 points
    const int b    = bg >> 2;

    // neighbor indices: thread-contiguous 64B via int4
    int idx[K_];
    {
        const int4* ip = (const int4*)(nidx + (size_t)(b*N_ + n) * K_);
        #pragma unroll
        for (int q4 = 0; q4 < K_/4; ++q4) {
            const int4 v = ip[q4];
            idx[q4*4+0] = v.x; idx[q4*4+1] = v.y;
            idx[q4*4+2] = v.z; idx[q4*4+3] = v.w;
        }
    }

    // ---- Pass A: attention logits from point-major q slab ----
    const float4* qslab = (const float4*)(qT + (size_t)bg * N_ * 16);
    const float4 lq0 = qslab[(size_t)n*4+0];
    const float4 lq1 = qslab[(size_t)n*4+1];
    const float4 lq2 = qslab[(size_t)n*4+2];
    const float4 lq3 = qslab[(size_t)n*4+3];

    float la[K_];
    #pragma unroll 4
    for (int k = 0; k < K_; ++k) {
        const float4* qj = qslab + (size_t)idx[k]*4;   // one 64B line
        const float4 a = qj[0], bq = qj[1], cq = qj[2], dq = qj[3];
        float s;
        s = lq0.x*a.x;            s = fmaf(lq0.y, a.y, s);
        s = fmaf(lq0.z, a.z, s);  s = fmaf(lq0.w, a.w, s);
        s = fmaf(lq1.x, bq.x, s); s = fmaf(lq1.y, bq.y, s);
        s = fmaf(lq1.z, bq.z, s); s = fmaf(lq1.w, bq.w, s);
        s = fmaf(lq2.x, cq.x, s); s = fmaf(lq2.y, cq.y, s);
        s = fmaf(lq2.z, cq.z, s); s = fmaf(lq2.w, cq.w, s);
        s = fmaf(lq3.x, dq.x, s); s = fmaf(lq3.y, dq.y, s);
        s = fmaf(lq3.z, dq.z, s); s = fmaf(lq3.w, dq.w, s);
        la[k] = s;
    }

    // softmax over k
    float m = la[0];
    #pragma unroll
    for (int k = 1; k < K_; ++k) m = fmaxf(m, la[k]);
    float ssum = 0.f;
    #pragma unroll
    for (int k = 0; k < K_; ++k) { const float e = __expf(la[k] - m); la[k] = e; ssum += e; }
    const float inv = 1.f / ssum;
    #pragma unroll
    for (int k = 0; k < K_; ++k) la[k] *= inv;

    // centrality scatter-add (bg region is XCD-local after swizzle)
    {
        float* cb = cent + (size_t)bg * N_;
        #pragma unroll
        for (int k = 0; k < K_; ++k) atomicAdd(cb + idx[k], la[k]);
    }

    // center coords + k-invariant LPE base
    const float4 cpt = xyz4[(size_t)b*N_ + n];
    float basec[CLPE_];
    #pragma unroll
    for (int c = 0; c < CLPE_; ++c) {
        const float4 a = sA[c];
        basec[c] = fmaf(a.x, cpt.x, fmaf(a.y, cpt.y, fmaf(a.z, cpt.z, a.w)));
    }

    // ---- Pass B1: gather neighbor xyz (+dist) and values ----
    const float4* vslab = (const float4*)(vT + (size_t)bg * N_ * 16);
    float4 nbr[K_];          // (nx, ny, nz, dist)
    float accV[CVG_];
    #pragma unroll
    for (int c = 0; c < CVG_; ++c) accV[c] = 0.f;

    #pragma unroll 2
    for (int k = 0; k < K_; ++k) {
        const int j = idx[k];
        const float4 p = xyz4[(size_t)b*N_ + j];
        const float rx = cpt.x - p.x, ry = cpt.y - p.y, rz = cpt.z - p.z;
        const float d  = sqrtf(fmaf(rx,rx, fmaf(ry,ry, rz*rz)));
        nbr[k] = make_float4(p.x, p.y, p.z, d);
        const float w = la[k];
        const float4* vj = vslab + (size_t)j*4;        // one 64B line
        const float4 v0 = vj[0], v1 = vj[1], v2 = vj[2], v3 = vj[3];
        accV[0]  = fmaf(w, v0.x, accV[0]);  accV[1]  = fmaf(w, v0.y, accV[1]);
        accV[2]  = fmaf(w, v0.z, accV[2]);  accV[3]  = fmaf(w, v0.w, accV[3]);
        accV[4]  = fmaf(w, v1.x, accV[4]);  accV[5]  = fmaf(w, v1.y, accV[5]);
        accV[6]  = fmaf(w, v1.z, accV[6]);  accV[7]  = fmaf(w, v1.w, accV[7]);
        accV[8]  = fmaf(w, v2.x, accV[8]);  accV[9]  = fmaf(w, v2.y, accV[9]);
        accV[10] = fmaf(w, v2.z, accV[10]); accV[11] = fmaf(w, v2.w, accV[11]);
        accV[12] = fmaf(w, v3.x, accV[12]); accV[13] = fmaf(w, v3.y, accV[13]);
        accV[14] = fmaf(w, v3.z, accV[14]); accV[15] = fmaf(w, v3.w, accV[15]);
    }

    // ---- Pass B2: per-channel enc, full-line non-temporal stores ----
    float* fe = fenc + ((size_t)bg * CLPE_ * N_ + n) * K_;
    float* ob = out  + (size_t)bg * (CVG_ + CLPE_) * N_ + n;

    #pragma unroll 2
    for (int c = 0; c < CLPE_; ++c) {
        const float4 wB = sB[c];
        const float base = basec[c];
        float e[K_];
        float acc = 0.f;
        #pragma unroll
        for (int k = 0; k < K_; ++k) {
            const float4 p = nbr[k];
            float tt = base;
            tt = fmaf(wB.x, p.x, tt);
            tt = fmaf(wB.y, p.y, tt);
            tt = fmaf(wB.z, p.z, tt);
            tt = fmaf(wB.w, p.w, tt);
            tt = fmaxf(tt, 0.f);
            e[k] = tt;
            acc  = fmaf(la[k], tt, acc);
        }
        float* fo = fe + (size_t)c * (N_ * K_);   // thread-owned 64B line
        nt_store4(fo + 0,  e[0],  e[1],  e[2],  e[3]);
        nt_store4(fo + 4,  e[4],  e[5],  e[6],  e[7]);
        nt_store4(fo + 8,  e[8],  e[9],  e[10], e[11]);
        nt_store4(fo + 12, e[12], e[13], e[14], e[15]);
        nt_store1(ob + (size_t)(CVG_ + c) * N_, acc);   // out enc-half
    }

    // out value-half
    #pragma unroll
    for (int c = 0; c < CVG_; ++c) nt_store1(ob + (size_t)c * N_, accV[c]);
}

// ---------------------------------------------------------------------------
// Fallback (verified correct) if workspace is too small.
// ---------------------------------------------------------------------------
__global__ __launch_bounds__(256) void gtl_fallback(
    const float* __restrict__ xyz,
    const float* __restrict__ query,
    const float* __restrict__ value,
    const int*   __restrict__ nidx,
    const float* __restrict__ lpeW,
    const float* __restrict__ lpeB,
    const float* __restrict__ bnG,
    const float* __restrict__ bnB,
    const float* __restrict__ bnM,
    const float* __restrict__ bnV,
    float* __restrict__ out,
    float* __restrict__ fenc,
    float* __restrict__ cent)
{
    __shared__ float4 sA[CLPE_];
    __shared__ float4 sB[CLPE_];
    const int t = threadIdx.x;
    if (t < CLPE_) {
        const float scale = bnG[t] * rsqrtf(bnV[t] + 1e-5f);
        const float shift = (lpeB[t] - bnM[t]) * scale + bnB[t];
        const float w0 = lpeW[t*10+0];
        const float w1 = lpeW[t*10+1], w2 = lpeW[t*10+2], w3 = lpeW[t*10+3];
        const float w4 = lpeW[t*10+4], w5 = lpeW[t*10+5], w6 = lpeW[t*10+6];
        const float w7 = lpeW[t*10+7], w8 = lpeW[t*10+8], w9 = lpeW[t*10+9];
        sA[t] = make_float4(scale*(w1+w4), scale*(w2+w5), scale*(w3+w6), shift);
        sB[t] = make_float4(scale*(w7-w1), scale*(w8-w2), scale*(w9-w3), scale*w0);
    }
    __syncthreads();
    const int gid = blockIdx.x * 256 + t;
    const int n   = gid & (N_ - 1);
    const int bg  = gid >> 14;
    const int g   = bg & (G_ - 1);
    const int b   = bg >> 2;
    const float cx = xyz[(size_t)(b*N_ + n)*3 + 0];
    const float cy = xyz[(size_t)(b*N_ + n)*3 + 1];
    const float cz = xyz[(size_t)(b*N_ + n)*3 + 2];
    int idx[K_];
    const int4* ip = (const int4*)(nidx + (size_t)(b*N_ + n) * K_);
    #pragma unroll
    for (int q4 = 0; q4 < K_/4; ++q4) {
        const int4 v = ip[q4];
        idx[q4*4+0] = v.x; idx[q4*4+1] = v.y; idx[q4*4+2] = v.z; idx[q4*4+3] = v.w;
    }
    const float* qb = query + (size_t)b*CQ_*N_ + (size_t)g*CQG_*N_;
    float lq[CQG_];
    #pragma unroll
    for (int c = 0; c < CQG_; ++c) lq[c] = qb[(size_t)c*N_ + n];
    float la[K_];
    #pragma unroll 4
    for (int k = 0; k < K_; ++k) {
        const float* qj = qb + idx[k];
        float s = 0.f;
        #pragma unroll
        for (int c = 0; c < CQG_; ++c) s = fmaf(lq[c], qj[(size_t)c*N_], s);
        la[k] = s;
    }
    float m = la[0];
    #pragma unroll
    for (int k = 1; k < K_; ++k) m = fmaxf(m, la[k]);
    float ssum = 0.f;
    #pragma unroll
    for (int k = 0; k < K_; ++k) { const float e = __expf(la[k] - m); la[k] = e; ssum += e; }
    const float inv = 1.f / ssum;
    #pragma unroll
    for (int k = 0; k < K_; ++k) la[k] *= inv;
    float* cb = cent + (size_t)bg * N_;
    #pragma unroll
    for (int k = 0; k < K_; ++k) atomicAdd(cb + idx[k], la[k]);
    float basec[CLPE_];
    #pragma unroll
    for (int c = 0; c < CLPE_; ++c) {
        const float4 a = sA[c];
        basec[c] = fmaf(a.x, cx, fmaf(a.y, cy, fmaf(a.z, cz, a.w)));
    }
    const float* vb = value + (size_t)b*CV_*N_ + (size_t)g*CVG_*N_;
    float accV[CVG_], accE[CLPE_];
    #pragma unroll
    for (int c = 0; c < CLPE_; ++c) { accV[c] = 0.f; accE[c] = 0.f; }
    float* fe = fenc + ((size_t)bg * CLPE_ * N_ + n) * K_;
    #pragma unroll 2
    for (int k = 0; k < K_; ++k) {
        const int j = idx[k];
        const float nx = xyz[(size_t)(b*N_ + j)*3 + 0];
        const float ny = xyz[(size_t)(b*N_ + j)*3 + 1];
        const float nz = xyz[(size_t)(b*N_ + j)*3 + 2];
        const float rx = cx - nx, ry = cy - ny, rz = cz - nz;
        const float d  = sqrtf(rx*rx + ry*ry + rz*rz);
        const float w  = la[k];
        const float* vj = vb + j;
        #pragma unroll
        for (int c = 0; c < CLPE_; ++c) {
            const float4 bb = sB[c];
            float e = basec[c];
            e = fmaf(bb.x, nx, e); e = fmaf(bb.y, ny, e);
            e = fmaf(bb.z, nz, e); e = fmaf(bb.w, d,  e);
            e = fmaxf(e, 0.f);
            fe[(size_t)c*(N_*K_) + k] = e;
            accE[c] = fmaf(w, e, accE[c]);
            accV[c] = fmaf(w, vj[(size_t)c*N_], accV[c]);
        }
    }
    float* ob = out + (size_t)bg * (CVG_ + CLPE_) * N_ + n;
    #pragma unroll
    for (int c = 0; c < CVG_; ++c)  ob[(size_t)c*N_]        = accV[c];
    #pragma unroll
    for (int c = 0; c < CLPE_; ++c) ob[(size_t)(CVG_+c)*N_] = accE[c];
}

extern "C" void kernel_launch(void* const* d_in, const int* in_sizes, int n_in,
                              void* d_out, int out_size, void* d_ws, size_t ws_size,
                              hipStream_t stream) {
    (void)in_sizes; (void)n_in; (void)out_size;

    const float* xyz   = (const float*)d_in[0];
    const float* query = (const float*)d_in[1];
    const float* value = (const float*)d_in[2];
    const int*   nidx  = (const int*)  d_in[3];
    const float* lpeW  = (const float*)d_in[5];
    const float* lpeB  = (const float*)d_in[6];
    const float* bnG   = (const float*)d_in[7];
    const float* bnB   = (const float*)d_in[8];
    const float* bnM   = (const float*)d_in[9];
    const float* bnV   = (const float*)d_in[10];

    float* out  = (float*)d_out;                                  // B*128*N
    float* fenc = out  + (size_t)B_ * (G_*(CVG_+CLPE_)) * N_;     // B*G*16*N*K
    float* cent = fenc + (size_t)B_ * G_ * CLPE_ * N_ * K_;       // B*G*N

    const size_t qT_bytes   = (size_t)NT_ * 16 * sizeof(float);   // 33.5 MB
    const size_t vT_bytes   = qT_bytes;
    const size_t xyz4_bytes = (size_t)B_ * N_ * sizeof(float4);   // 2 MB
    const size_t need = qT_bytes + vT_bytes + xyz4_bytes;

    if (ws_size >= need) {
        float*  qT   = (float*)d_ws;
        float*  vT   = qT + (size_t)NT_ * 16;
        float4* xyz4 = (float4*)(vT + (size_t)NT_ * 16);
        const int prep_grid = NT_ / 64;    // 8192 blocks (64 pts each)
        const int main_grid = NT_ / 256;   // 2048 blocks
        hipLaunchKernelGGL(gtl_prep, dim3(prep_grid), dim3(256), 0, stream,
                           query, value, xyz, (float4*)qT, (float4*)vT, xyz4, cent);
        hipLaunchKernelGGL(gtl_main, dim3(main_grid), dim3(256), 0, stream,
                           qT, vT, xyz4, nidx, lpeW, lpeB, bnG, bnB, bnM, bnV,
                           out, fenc, cent);
    } else {
        hipMemsetAsync(cent, 0, sizeof(float) * (size_t)B_ * G_ * N_, stream);
        hipLaunchKernelGGL(gtl_fallback, dim3(NT_/256), dim3(256), 0, stream,
                           xyz, query, value, nidx, lpeW, lpeB, bnG, bnB, bnM, bnV,
                           out, fenc, cent);
    }
}

// Round 2
// 1204.032 us; speedup vs baseline: 1.0235x; 1.0235x over previous
//
#include <hip/hip_runtime.h>
#include <hip/hip_fp16.h>

#define B_    8
#define N_    16384
#define K_    16
#define G_    4
#define CQ_   64
#define CV_   64
#define CQG_  16
#define CVG_  16
#define CLPE_ 16
#define NT_   (B_*G_*N_)   // 524288 threads, one per (b,g,n)

typedef float f4v __attribute__((ext_vector_type(4)));

static __device__ __forceinline__ void nt_store4(float* p, float a, float b,
                                                 float c, float d) {
    f4v v = {a, b, c, d};
    __builtin_nontemporal_store(v, (f4v*)p);
}
static __device__ __forceinline__ void nt_store1(float* p, float a) {
    __builtin_nontemporal_store(a, p);
}

union QV { uint4 u; __half2 h[4]; };

// ---------------------------------------------------------------------------
// Kernel 1: transpose + fp16-pack. One thread per (bg,n). Builds qvT records:
// per (bg,n) 64B = [16 x half q | 16 x half v]. Also packs xyz -> float4 and
// zeroes cent. Reads 256B-coalesced per wave instr, writes full 64B lines.
// ---------------------------------------------------------------------------
__global__ __launch_bounds__(256) void gtl_prep(
    const float* __restrict__ query,
    const float* __restrict__ value,
    const float* __restrict__ xyz,
    uint4*  __restrict__ qvT,
    float4* __restrict__ xyz4,
    float*  __restrict__ cent)
{
    const int gid = blockIdx.x * 256 + threadIdx.x;   // == bg*N + n
    const int n   = gid & (N_ - 1);
    const int bg  = gid >> 14;
    const int g   = bg & (G_ - 1);
    const int b   = bg >> 2;

    const float* qb = query + (size_t)b*CQ_*N_ + (size_t)g*CQG_*N_ + n;
    const float* vb = value + (size_t)b*CV_*N_ + (size_t)g*CVG_*N_ + n;

    uint u[16];
    #pragma unroll
    for (int i = 0; i < 8; ++i) {
        const float a0 = qb[(size_t)(2*i+0)*N_];
        const float a1 = qb[(size_t)(2*i+1)*N_];
        const __half2 h = __floats2half2_rn(a0, a1);
        u[i] = *(const uint*)&h;
    }
    #pragma unroll
    for (int i = 0; i < 8; ++i) {
        const float a0 = vb[(size_t)(2*i+0)*N_];
        const float a1 = vb[(size_t)(2*i+1)*N_];
        const __half2 h = __floats2half2_rn(a0, a1);
        u[8+i] = *(const uint*)&h;
    }

    uint4* o = qvT + (size_t)gid * 4;
    o[0] = make_uint4(u[0],  u[1],  u[2],  u[3]);   // q ch 0..7
    o[1] = make_uint4(u[4],  u[5],  u[6],  u[7]);   // q ch 8..15
    o[2] = make_uint4(u[8],  u[9],  u[10], u[11]);  // v ch 0..7
    o[3] = make_uint4(u[12], u[13], u[14], u[15]);  // v ch 8..15

    cent[gid] = 0.f;

    if (g == 0) {
        const size_t pp = (size_t)b*N_ + n;
        xyz4[pp] = make_float4(xyz[pp*3+0], xyz[pp*3+1], xyz[pp*3+2], 0.f);
    }
}

// ---------------------------------------------------------------------------
// Kernel 2: main fused pass. One thread per (b,g,n).
// XCD-chunked swizzle (2048 blocks = 8 XCDs x 256 slots); per-XCD hot set =
// ~2.5 resident qv slabs (1MB each) + xyz4 + cent -> fits 4MB L2.
// Neighbor gathers: 2x dwordx4 (q half), 2x dwordx4 (v half), 1x xyz4 ->
// 80 divergent gather instrs/thread (was 144).
// ---------------------------------------------------------------------------
__global__ __launch_bounds__(256) void gtl_main(
    const uint4*  __restrict__ qvT,
    const float4* __restrict__ xyz4,
    const int*    __restrict__ nidx,
    const float*  __restrict__ lpeW,
    const float*  __restrict__ lpeB,
    const float*  __restrict__ bnG,
    const float*  __restrict__ bnB,
    const float*  __restrict__ bnM,
    const float*  __restrict__ bnV,
    float* __restrict__ out,
    float* __restrict__ fenc,
    float* __restrict__ cent)
{
    // Folded LPE+BN weights:
    __shared__ float4 sA[CLPE_];  // scale*(center xyz coeffs), w = shift
    __shared__ float4 sB[CLPE_];  // scale*(neighbor xyz coeffs), w = scale*w0

    const int t = threadIdx.x;
    if (t < CLPE_) {
        const float scale = bnG[t] * rsqrtf(bnV[t] + 1e-5f);
        const float shift = (lpeB[t] - bnM[t]) * scale + bnB[t];
        const float w0 = lpeW[t*10+0];
        const float w1 = lpeW[t*10+1], w2 = lpeW[t*10+2], w3 = lpeW[t*10+3];
        const float w4 = lpeW[t*10+4], w5 = lpeW[t*10+5], w6 = lpeW[t*10+6];
        const float w7 = lpeW[t*10+7], w8 = lpeW[t*10+8], w9 = lpeW[t*10+9];
        sA[t] = make_float4(scale*(w1+w4), scale*(w2+w5), scale*(w3+w6), shift);
        sB[t] = make_float4(scale*(w7-w1), scale*(w8-w2), scale*(w9-w3), scale*w0);
    }
    __syncthreads();

    // XCD-chunked work mapping (2048 blocks = 8 XCDs x 256 slots)
    const int wid  = blockIdx.x;
    const int xcd  = wid & 7;
    const int slot = wid >> 3;                 // 0..255 per XCD
    const int bg   = (xcd << 2) | (slot >> 6); // 4 bgs per XCD, same b
    const int n    = ((slot & 63) << 8) | t;   // 64 tiles x 256 points
    const int b    = bg >> 2;

    // neighbor indices: thread-contiguous 64B via int4
    int idx[K_];
    {
        const int4* ip = (const int4*)(nidx + (size_t)(b*N_ + n) * K_);
        #pragma unroll
        for (int q4 = 0; q4 < K_/4; ++q4) {
            const int4 v = ip[q4];
            idx[q4*4+0] = v.x; idx[q4*4+1] = v.y;
            idx[q4*4+2] = v.z; idx[q4*4+3] = v.w;
        }
    }

    const uint4* qvslab = qvT + (size_t)bg * N_ * 4;

    // center q -> f32 registers
    float lq[CQG_];
    {
        QV cA, cB;
        cA.u = qvslab[(size_t)n*4+0];
        cB.u = qvslab[(size_t)n*4+1];
        #pragma unroll
        for (int i = 0; i < 4; ++i) {
            const float2 f = __half22float2(cA.h[i]);
            lq[2*i+0] = f.x; lq[2*i+1] = f.y;
        }
        #pragma unroll
        for (int i = 0; i < 4; ++i) {
            const float2 f = __half22float2(cB.h[i]);
            lq[8+2*i+0] = f.x; lq[8+2*i+1] = f.y;
        }
    }

    // ---- Pass A: attention logits (q half of neighbor record: 32B) ----
    float la[K_];
    #pragma unroll 4
    for (int k = 0; k < K_; ++k) {
        const uint4* qj = qvslab + (size_t)idx[k]*4;
        QV a, b2;
        a.u  = qj[0];
        b2.u = qj[1];
        float s = 0.f;
        #pragma unroll
        for (int i = 0; i < 4; ++i) {
            const float2 f = __half22float2(a.h[i]);
            s = fmaf(lq[2*i+0], f.x, s);
            s = fmaf(lq[2*i+1], f.y, s);
        }
        #pragma unroll
        for (int i = 0; i < 4; ++i) {
            const float2 f = __half22float2(b2.h[i]);
            s = fmaf(lq[8+2*i+0], f.x, s);
            s = fmaf(lq[8+2*i+1], f.y, s);
        }
        la[k] = s;
    }

    // softmax over k
    float m = la[0];
    #pragma unroll
    for (int k = 1; k < K_; ++k) m = fmaxf(m, la[k]);
    float ssum = 0.f;
    #pragma unroll
    for (int k = 0; k < K_; ++k) { const float e = __expf(la[k] - m); la[k] = e; ssum += e; }
    const float inv = 1.f / ssum;
    #pragma unroll
    for (int k = 0; k < K_; ++k) la[k] *= inv;

    // centrality scatter-add (bg region is XCD-local after swizzle)
    {
        float* cb = cent + (size_t)bg * N_;
        #pragma unroll
        for (int k = 0; k < K_; ++k) atomicAdd(cb + idx[k], la[k]);
    }

    // center coords + k-invariant LPE base
    const float4 cpt = xyz4[(size_t)b*N_ + n];
    float basec[CLPE_];
    #pragma unroll
    for (int c = 0; c < CLPE_; ++c) {
        const float4 a = sA[c];
        basec[c] = fmaf(a.x, cpt.x, fmaf(a.y, cpt.y, fmaf(a.z, cpt.z, a.w)));
    }

    // ---- Pass B1: gather neighbor xyz (+dist) and v half (32B) ----
    float4 nbr[K_];          // (nx, ny, nz, dist)
    float accV[CVG_];
    #pragma unroll
    for (int c = 0; c < CVG_; ++c) accV[c] = 0.f;

    #pragma unroll 4
    for (int k = 0; k < K_; ++k) {
        const int j = idx[k];
        const float4 p = xyz4[(size_t)b*N_ + j];
        const float rx = cpt.x - p.x, ry = cpt.y - p.y, rz = cpt.z - p.z;
        const float d  = sqrtf(fmaf(rx,rx, fmaf(ry,ry, rz*rz)));
        nbr[k] = make_float4(p.x, p.y, p.z, d);
        const float w = la[k];
        const uint4* vj = qvslab + (size_t)j*4 + 2;
        QV v0, v1;
        v0.u = vj[0];
        v1.u = vj[1];
        #pragma unroll
        for (int i = 0; i < 4; ++i) {
            const float2 f = __half22float2(v0.h[i]);
            accV[2*i+0] = fmaf(w, f.x, accV[2*i+0]);
            accV[2*i+1] = fmaf(w, f.y, accV[2*i+1]);
        }
        #pragma unroll
        for (int i = 0; i < 4; ++i) {
            const float2 f = __half22float2(v1.h[i]);
            accV[8+2*i+0] = fmaf(w, f.x, accV[8+2*i+0]);
            accV[8+2*i+1] = fmaf(w, f.y, accV[8+2*i+1]);
        }
    }

    // ---- Pass B2: per-channel enc, full-line non-temporal stores ----
    float* fe = fenc + ((size_t)bg * CLPE_ * N_ + n) * K_;
    float* ob = out  + (size_t)bg * (CVG_ + CLPE_) * N_ + n;

    #pragma unroll 2
    for (int c = 0; c < CLPE_; ++c) {
        const float4 wB = sB[c];
        const float base = basec[c];
        float e[K_];
        float acc = 0.f;
        #pragma unroll
        for (int k = 0; k < K_; ++k) {
            const float4 p = nbr[k];
            float tt = base;
            tt = fmaf(wB.x, p.x, tt);
            tt = fmaf(wB.y, p.y, tt);
            tt = fmaf(wB.z, p.z, tt);
            tt = fmaf(wB.w, p.w, tt);
            tt = fmaxf(tt, 0.f);
            e[k] = tt;
            acc  = fmaf(la[k], tt, acc);
        }
        float* fo = fe + (size_t)c * (N_ * K_);   // thread-owned 64B line
        nt_store4(fo + 0,  e[0],  e[1],  e[2],  e[3]);
        nt_store4(fo + 4,  e[4],  e[5],  e[6],  e[7]);
        nt_store4(fo + 8,  e[8],  e[9],  e[10], e[11]);
        nt_store4(fo + 12, e[12], e[13], e[14], e[15]);
        nt_store1(ob + (size_t)(CVG_ + c) * N_, acc);   // out enc-half
    }

    // out value-half
    #pragma unroll
    for (int c = 0; c < CVG_; ++c) nt_store1(ob + (size_t)c * N_, accV[c]);
}

// ---------------------------------------------------------------------------
// Fallback (verified correct, fp32) if workspace is too small.
// ---------------------------------------------------------------------------
__global__ __launch_bounds__(256) void gtl_fallback(
    const float* __restrict__ xyz,
    const float* __restrict__ query,
    const float* __restrict__ value,
    const int*   __restrict__ nidx,
    const float* __restrict__ lpeW,
    const float* __restrict__ lpeB,
    const float* __restrict__ bnG,
    const float* __restrict__ bnB,
    const float* __restrict__ bnM,
    const float* __restrict__ bnV,
    float* __restrict__ out,
    float* __restrict__ fenc,
    float* __restrict__ cent)
{
    __shared__ float4 sA[CLPE_];
    __shared__ float4 sB[CLPE_];
    const int t = threadIdx.x;
    if (t < CLPE_) {
        const float scale = bnG[t] * rsqrtf(bnV[t] + 1e-5f);
        const float shift = (lpeB[t] - bnM[t]) * scale + bnB[t];
        const float w0 = lpeW[t*10+0];
        const float w1 = lpeW[t*10+1], w2 = lpeW[t*10+2], w3 = lpeW[t*10+3];
        const float w4 = lpeW[t*10+4], w5 = lpeW[t*10+5], w6 = lpeW[t*10+6];
        const float w7 = lpeW[t*10+7], w8 = lpeW[t*10+8], w9 = lpeW[t*10+9];
        sA[t] = make_float4(scale*(w1+w4), scale*(w2+w5), scale*(w3+w6), shift);
        sB[t] = make_float4(scale*(w7-w1), scale*(w8-w2), scale*(w9-w3), scale*w0);
    }
    __syncthreads();
    const int gid = blockIdx.x * 256 + t;
    const int n   = gid & (N_ - 1);
    const int bg  = gid >> 14;
    const int g   = bg & (G_ - 1);
    const int b   = bg >> 2;
    const float cx = xyz[(size_t)(b*N_ + n)*3 + 0];
    const float cy = xyz[(size_t)(b*N_ + n)*3 + 1];
    const float cz = xyz[(size_t)(b*N_ + n)*3 + 2];
    int idx[K_];
    const int4* ip = (const int4*)(nidx + (size_t)(b*N_ + n) * K_);
    #pragma unroll
    for (int q4 = 0; q4 < K_/4; ++q4) {
        const int4 v = ip[q4];
        idx[q4*4+0] = v.x; idx[q4*4+1] = v.y; idx[q4*4+2] = v.z; idx[q4*4+3] = v.w;
    }
    const float* qb = query + (size_t)b*CQ_*N_ + (size_t)g*CQG_*N_;
    float lq[CQG_];
    #pragma unroll
    for (int c = 0; c < CQG_; ++c) lq[c] = qb[(size_t)c*N_ + n];
    float la[K_];
    #pragma unroll 4
    for (int k = 0; k < K_; ++k) {
        const float* qj = qb + idx[k];
        float s = 0.f;
        #pragma unroll
        for (int c = 0; c < CQG_; ++c) s = fmaf(lq[c], qj[(size_t)c*N_], s);
        la[k] = s;
    }
    float m = la[0];
    #pragma unroll
    for (int k = 1; k < K_; ++k) m = fmaxf(m, la[k]);
    float ssum = 0.f;
    #pragma unroll
    for (int k = 0; k < K_; ++k) { const float e = __expf(la[k] - m); la[k] = e; ssum += e; }
    const float inv = 1.f / ssum;
    #pragma unroll
    for (int k = 0; k < K_; ++k) la[k] *= inv;
    float* cb = cent + (size_t)bg * N_;
    #pragma unroll
    for (int k = 0; k < K_; ++k) atomicAdd(cb + idx[k], la[k]);
    float basec[CLPE_];
    #pragma unroll
    for (int c = 0; c < CLPE_; ++c) {
        const float4 a = sA[c];
        basec[c] = fmaf(a.x, cx, fmaf(a.y, cy, fmaf(a.z, cz, a.w)));
    }
    const float* vb = value + (size_t)b*CV_*N_ + (size_t)g*CVG_*N_;
    float accV[CVG_], accE[CLPE_];
    #pragma unroll
    for (int c = 0; c < CLPE_; ++c) { accV[c] = 0.f; accE[c] = 0.f; }
    float* fe = fenc + ((size_t)bg * CLPE_ * N_ + n) * K_;
    #pragma unroll 2
    for (int k = 0; k < K_; ++k) {
        const int j = idx[k];
        const float nx = xyz[(size_t)(b*N_ + j)*3 + 0];
        const float ny = xyz[(size_t)(b*N_ + j)*3 + 1];
        const float nz = xyz[(size_t)(b*N_ + j)*3 + 2];
        const float rx = cx - nx, ry = cy - ny, rz = cz - nz;
        const float d  = sqrtf(rx*rx + ry*ry + rz*rz);
        const float w  = la[k];
        const float* vj = vb + j;
        #pragma unroll
        for (int c = 0; c < CLPE_; ++c) {
            const float4 bb = sB[c];
            float e = basec[c];
            e = fmaf(bb.x, nx, e); e = fmaf(bb.y, ny, e);
            e = fmaf(bb.z, nz, e); e = fmaf(bb.w, d,  e);
            e = fmaxf(e, 0.f);
            fe[(size_t)c*(N_*K_) + k] = e;
            accE[c] = fmaf(w, e, accE[c]);
            accV[c] = fmaf(w, vj[(size_t)c*N_], accV[c]);
        }
    }
    float* ob = out + (size_t)bg * (CVG_ + CLPE_) * N_ + n;
    #pragma unroll
    for (int c = 0; c < CVG_; ++c)  ob[(size_t)c*N_]        = accV[c];
    #pragma unroll
    for (int c = 0; c < CLPE_; ++c) ob[(size_t)(CVG_+c)*N_] = accE[c];
}

extern "C" void kernel_launch(void* const* d_in, const int* in_sizes, int n_in,
                              void* d_out, int out_size, void* d_ws, size_t ws_size,
                              hipStream_t stream) {
    (void)in_sizes; (void)n_in; (void)out_size;

    const float* xyz   = (const float*)d_in[0];
    const float* query = (const float*)d_in[1];
    const float* value = (const float*)d_in[2];
    const int*   nidx  = (const int*)  d_in[3];
    const float* lpeW  = (const float*)d_in[5];
    const float* lpeB  = (const float*)d_in[6];
    const float* bnG   = (const float*)d_in[7];
    const float* bnB   = (const float*)d_in[8];
    const float* bnM   = (const float*)d_in[9];
    const float* bnV   = (const float*)d_in[10];

    float* out  = (float*)d_out;                                  // B*128*N
    float* fenc = out  + (size_t)B_ * (G_*(CVG_+CLPE_)) * N_;     // B*G*16*N*K
    float* cent = fenc + (size_t)B_ * G_ * CLPE_ * N_ * K_;       // B*G*N

    const size_t qv_bytes   = (size_t)NT_ * 64;                   // 33.5 MB
    const size_t xyz4_bytes = (size_t)B_ * N_ * sizeof(float4);   // 2 MB
    const size_t need = qv_bytes + xyz4_bytes;

    const int grid = NT_ / 256;   // 2048 blocks

    if (ws_size >= need) {
        uint4*  qvT  = (uint4*)d_ws;
        float4* xyz4 = (float4*)((char*)d_ws + qv_bytes);
        hipLaunchKernelGGL(gtl_prep, dim3(grid), dim3(256), 0, stream,
                           query, value, xyz, qvT, xyz4, cent);
        hipLaunchKernelGGL(gtl_main, dim3(grid), dim3(256), 0, stream,
                           qvT, xyz4, nidx, lpeW, lpeB, bnG, bnB, bnM, bnV,
                           out, fenc, cent);
    } else {
        hipMemsetAsync(cent, 0, sizeof(float) * (size_t)B_ * G_ * N_, stream);
        hipLaunchKernelGGL(gtl_fallback, dim3(grid), dim3(256), 0, stream,
                           xyz, query, value, nidx, lpeW, lpeB, bnG, bnB, bnM, bnV,
                           out, fenc, cent);
    }
}

// Round 5
// 1136.351 us; speedup vs baseline: 1.0844x; 1.0596x over previous
//
#include <hip/hip_runtime.h>
#include <hip/hip_fp16.h>

#define B_    8
#define N_    16384
#define K_    16
#define G_    4
#define CQ_   64
#define CV_   64
#define CQG_  16
#define CVG_  16
#define CLPE_ 16
#define NT_   (B_*G_*N_)   // 524288 threads, one per (b,g,n)

typedef float f4v __attribute__((ext_vector_type(4)));
typedef int   i4v __attribute__((ext_vector_type(4)));

static __device__ __forceinline__ void nt_store4(float* p, float a, float b,
                                                 float c, float d) {
    f4v v = {a, b, c, d};
    __builtin_nontemporal_store(v, (f4v*)p);
}
static __device__ __forceinline__ void nt_store1(float* p, float a) {
    __builtin_nontemporal_store(a, p);
}

union QV { uint4 u; __half2 h[4]; };

// ---------------------------------------------------------------------------
// Kernel 1: transpose + fp16-pack. XCD-aligned mapping: block (xcd,i) handles
// bg = (xcd<<2)|(i>>6) -- the same bg that gtl_main's XCD xcd will consume, so
// the qv slab is produced into the consuming XCD's L2. Record per (bg,n):
// 64B = [16 x half q | 16 x half v]. Also packs xyz -> float4, zeroes cent.
// ---------------------------------------------------------------------------
__global__ __launch_bounds__(256) void gtl_prep(
    const float* __restrict__ query,
    const float* __restrict__ value,
    const float* __restrict__ xyz,
    uint4*  __restrict__ qvT,
    float4* __restrict__ xyz4,
    float*  __restrict__ cent)
{
    const int wid = blockIdx.x;          // 0..2047
    const int xcd = wid & 7;
    const int i   = wid >> 3;            // 0..255
    const int bg  = (xcd << 2) | (i >> 6);
    const int n   = ((i & 63) << 8) | threadIdx.x;
    const int g   = bg & (G_ - 1);
    const int b   = bg >> 2;
    const int gid = (bg << 14) | n;

    const float* qb = query + (size_t)b*CQ_*N_ + (size_t)g*CQG_*N_ + n;
    const float* vb = value + (size_t)b*CV_*N_ + (size_t)g*CVG_*N_ + n;

    uint u[16];
    #pragma unroll
    for (int q2 = 0; q2 < 8; ++q2) {
        const float a0 = qb[(size_t)(2*q2+0)*N_];
        const float a1 = qb[(size_t)(2*q2+1)*N_];
        const __half2 h = __floats2half2_rn(a0, a1);
        u[q2] = *(const uint*)&h;
    }
    #pragma unroll
    for (int q2 = 0; q2 < 8; ++q2) {
        const float a0 = vb[(size_t)(2*q2+0)*N_];
        const float a1 = vb[(size_t)(2*q2+1)*N_];
        const __half2 h = __floats2half2_rn(a0, a1);
        u[8+q2] = *(const uint*)&h;
    }

    uint4* o = qvT + (size_t)gid * 4;
    o[0] = make_uint4(u[0],  u[1],  u[2],  u[3]);   // q ch 0..7
    o[1] = make_uint4(u[4],  u[5],  u[6],  u[7]);   // q ch 8..15
    o[2] = make_uint4(u[8],  u[9],  u[10], u[11]);  // v ch 0..7
    o[3] = make_uint4(u[12], u[13], u[14], u[15]);  // v ch 8..15

    cent[gid] = 0.f;

    if (g == 0) {
        const size_t pp = (size_t)b*N_ + n;
        xyz4[pp] = make_float4(xyz[pp*3+0], xyz[pp*3+1], xyz[pp*3+2], 0.f);
    }
}

// ---------------------------------------------------------------------------
// Kernel 2: fused main pass, online softmax. One thread per (b,g,n).
// 1024 blocks x 2 phased slots: XCD x runs bgs {4x,4x+1} then {4x+2,4x+3};
// per-phase hot set (2 qv slabs + xyz + cent) ~2.5MB < 4MB L2. nidx loads are
// non-temporal (streamed, no L2 allocate). Each neighbor record is gathered
// ONCE (64B line) -> 2 line-requests per k (qv + xyz), was 3.
// ---------------------------------------------------------------------------
__global__ __launch_bounds__(256) void gtl_main(
    const uint4*  __restrict__ qvT,
    const float4* __restrict__ xyz4,
    const int*    __restrict__ nidx,
    const float*  __restrict__ lpeW,
    const float*  __restrict__ lpeB,
    const float*  __restrict__ bnG,
    const float*  __restrict__ bnB,
    const float*  __restrict__ bnM,
    const float*  __restrict__ bnV,
    float* __restrict__ out,
    float* __restrict__ fenc,
    float* __restrict__ cent)
{
    __shared__ float4 sA[CLPE_];  // scale*(center xyz coeffs), w = shift
    __shared__ float4 sB[CLPE_];  // scale*(neighbor xyz coeffs), w = scale*w0

    const int t = threadIdx.x;
    if (t < CLPE_) {
        const float scale = bnG[t] * rsqrtf(bnV[t] + 1e-5f);
        const float shift = (lpeB[t] - bnM[t]) * scale + bnB[t];
        const float w0 = lpeW[t*10+0];
        const float w1 = lpeW[t*10+1], w2 = lpeW[t*10+2], w3 = lpeW[t*10+3];
        const float w4 = lpeW[t*10+4], w5 = lpeW[t*10+5], w6 = lpeW[t*10+6];
        const float w7 = lpeW[t*10+7], w8 = lpeW[t*10+8], w9 = lpeW[t*10+9];
        sA[t] = make_float4(scale*(w1+w4), scale*(w2+w5), scale*(w3+w6), shift);
        sB[t] = make_float4(scale*(w7-w1), scale*(w8-w2), scale*(w9-w3), scale*w0);
    }
    __syncthreads();

    const int wid  = blockIdx.x;    // 0..1023
    const int xcd  = wid & 7;
    const int half = wid >> 3;      // 0..127

    #pragma unroll 1
    for (int p = 0; p < 2; ++p) {
        const int slot = half + (p << 7);          // 0..255
        const int bg   = (xcd << 2) | (slot >> 6);
        const int n    = ((slot & 63) << 8) | t;
        const int b    = bg >> 2;
        const size_t xb = (size_t)b * N_;

        // neighbor indices (streamed once: non-temporal, keep out of L2)
        int idx[K_];
        {
            const i4v* ip = (const i4v*)(nidx + ((size_t)b*N_ + n) * K_);
            #pragma unroll
            for (int q4 = 0; q4 < K_/4; ++q4) {
                const i4v v = __builtin_nontemporal_load(ip + q4);
                idx[q4*4+0] = v.x; idx[q4*4+1] = v.y;
                idx[q4*4+2] = v.z; idx[q4*4+3] = v.w;
            }
        }

        const uint4* qvslab = qvT + (size_t)bg * N_ * 4;

        // center q -> f32 registers
        float lq[CQG_];
        {
            QV cA, cB;
            cA.u = qvslab[(size_t)n*4+0];
            cB.u = qvslab[(size_t)n*4+1];
            #pragma unroll
            for (int i2 = 0; i2 < 4; ++i2) {
                const float2 f = __half22float2(cA.h[i2]);
                lq[2*i2+0] = f.x; lq[2*i2+1] = f.y;
            }
            #pragma unroll
            for (int i2 = 0; i2 < 4; ++i2) {
                const float2 f = __half22float2(cB.h[i2]);
                lq[8+2*i2+0] = f.x; lq[8+2*i2+1] = f.y;
            }
        }
        const float4 cpt = xyz4[xb + n];

        // ---- fused gather + logits + online-softmax PV ----
        float la[K_];
        float accV[CVG_];
        __half2 nbh[2*K_];     // per k: (nx,ny),(nz,d) packed fp16
        #pragma unroll
        for (int c = 0; c < CVG_; ++c) accV[c] = 0.f;
        float m = -1e30f;

        #pragma unroll 4
        for (int k = 0; k < K_; ++k) {
            const int j = idx[k];
            const uint4* rp = qvslab + (size_t)j*4;   // one 64B line
            QV r0, r1, r2, r3;
            r0.u = rp[0]; r1.u = rp[1]; r2.u = rp[2]; r3.u = rp[3];
            const float4 pp = xyz4[xb + j];

            float s = 0.f;
            #pragma unroll
            for (int i2 = 0; i2 < 4; ++i2) {
                const float2 f = __half22float2(r0.h[i2]);
                s = fmaf(lq[2*i2+0], f.x, s);
                s = fmaf(lq[2*i2+1], f.y, s);
            }
            #pragma unroll
            for (int i2 = 0; i2 < 4; ++i2) {
                const float2 f = __half22float2(r1.h[i2]);
                s = fmaf(lq[8+2*i2+0], f.x, s);
                s = fmaf(lq[8+2*i2+1], f.y, s);
            }
            la[k] = s;

            const float mn = fmaxf(m, s);
            const float sc = __expf(m - mn);   // 0 on first k, 1 when max unchanged
            const float w  = __expf(s - mn);
            m = mn;

            #pragma unroll
            for (int i2 = 0; i2 < 4; ++i2) {
                const float2 f = __half22float2(r2.h[i2]);
                accV[2*i2+0] = fmaf(w, f.x, accV[2*i2+0]*sc);
                accV[2*i2+1] = fmaf(w, f.y, accV[2*i2+1]*sc);
            }
            #pragma unroll
            for (int i2 = 0; i2 < 4; ++i2) {
                const float2 f = __half22float2(r3.h[i2]);
                accV[8+2*i2+0] = fmaf(w, f.x, accV[8+2*i2+0]*sc);
                accV[8+2*i2+1] = fmaf(w, f.y, accV[8+2*i2+1]*sc);
            }

            const float rx = cpt.x - pp.x, ry = cpt.y - pp.y, rz = cpt.z - pp.z;
            const float d  = sqrtf(fmaf(rx,rx, fmaf(ry,ry, rz*rz)));
            nbh[2*k+0] = __floats2half2_rn(pp.x, pp.y);
            nbh[2*k+1] = __floats2half2_rn(pp.z, d);
        }

        // finish softmax: e_k = exp(s_k - m_final); accV already uses m_final
        float ssum = 0.f;
        #pragma unroll
        for (int k = 0; k < K_; ++k) {
            const float e = __expf(la[k] - m);
            la[k] = e; ssum += e;
        }
        const float inv = 1.f / ssum;
        #pragma unroll
        for (int k = 0; k < K_; ++k) la[k] *= inv;
        #pragma unroll
        for (int c = 0; c < CVG_; ++c) accV[c] *= inv;

        // centrality scatter-add (bg slab is XCD-local)
        {
            float* cb = cent + (size_t)bg * N_;
            #pragma unroll
            for (int k = 0; k < K_; ++k) atomicAdd(cb + idx[k], la[k]);
        }

        // k-invariant LPE base
        float basec[CLPE_];
        #pragma unroll
        for (int c = 0; c < CLPE_; ++c) {
            const float4 a = sA[c];
            basec[c] = fmaf(a.x, cpt.x, fmaf(a.y, cpt.y, fmaf(a.z, cpt.z, a.w)));
        }

        // ---- per-channel enc, full-line non-temporal stores ----
        float* fe = fenc + ((size_t)bg * CLPE_ * N_ + n) * K_;
        float* ob = out  + (size_t)bg * (CVG_ + CLPE_) * N_ + n;

        #pragma unroll 2
        for (int c = 0; c < CLPE_; ++c) {
            const float4 wB = sB[c];
            const float base = basec[c];
            float e[K_];
            float acc = 0.f;
            #pragma unroll
            for (int k = 0; k < K_; ++k) {
                const float2 pxy = __half22float2(nbh[2*k+0]);
                const float2 pzd = __half22float2(nbh[2*k+1]);
                float tt = base;
                tt = fmaf(wB.x, pxy.x, tt);
                tt = fmaf(wB.y, pxy.y, tt);
                tt = fmaf(wB.z, pzd.x, tt);
                tt = fmaf(wB.w, pzd.y, tt);
                tt = fmaxf(tt, 0.f);
                e[k] = tt;
                acc  = fmaf(la[k], tt, acc);
            }
            float* fo = fe + (size_t)c * (N_ * K_);   // thread-owned 64B line
            nt_store4(fo + 0,  e[0],  e[1],  e[2],  e[3]);
            nt_store4(fo + 4,  e[4],  e[5],  e[6],  e[7]);
            nt_store4(fo + 8,  e[8],  e[9],  e[10], e[11]);
            nt_store4(fo + 12, e[12], e[13], e[14], e[15]);
            nt_store1(ob + (size_t)(CVG_ + c) * N_, acc);
        }

        #pragma unroll
        for (int c = 0; c < CVG_; ++c) nt_store1(ob + (size_t)c * N_, accV[c]);
    }
}

// ---------------------------------------------------------------------------
// Fallback (verified correct, fp32) if workspace is too small.
// ---------------------------------------------------------------------------
__global__ __launch_bounds__(256) void gtl_fallback(
    const float* __restrict__ xyz,
    const float* __restrict__ query,
    const float* __restrict__ value,
    const int*   __restrict__ nidx,
    const float* __restrict__ lpeW,
    const float* __restrict__ lpeB,
    const float* __restrict__ bnG,
    const float* __restrict__ bnB,
    const float* __restrict__ bnM,
    const float* __restrict__ bnV,
    float* __restrict__ out,
    float* __restrict__ fenc,
    float* __restrict__ cent)
{
    __shared__ float4 sA[CLPE_];
    __shared__ float4 sB[CLPE_];
    const int t = threadIdx.x;
    if (t < CLPE_) {
        const float scale = bnG[t] * rsqrtf(bnV[t] + 1e-5f);
        const float shift = (lpeB[t] - bnM[t]) * scale + bnB[t];
        const float w0 = lpeW[t*10+0];
        const float w1 = lpeW[t*10+1], w2 = lpeW[t*10+2], w3 = lpeW[t*10+3];
        const float w4 = lpeW[t*10+4], w5 = lpeW[t*10+5], w6 = lpeW[t*10+6];
        const float w7 = lpeW[t*10+7], w8 = lpeW[t*10+8], w9 = lpeW[t*10+9];
        sA[t] = make_float4(scale*(w1+w4), scale*(w2+w5), scale*(w3+w6), shift);
        sB[t] = make_float4(scale*(w7-w1), scale*(w8-w2), scale*(w9-w3), scale*w0);
    }
    __syncthreads();
    const int gid = blockIdx.x * 256 + t;
    const int n   = gid & (N_ - 1);
    const int bg  = gid >> 14;
    const int g   = bg & (G_ - 1);
    const int b   = bg >> 2;
    const float cx = xyz[(size_t)(b*N_ + n)*3 + 0];
    const float cy = xyz[(size_t)(b*N_ + n)*3 + 1];
    const float cz = xyz[(size_t)(b*N_ + n)*3 + 2];
    int idx[K_];
    const int4* ip = (const int4*)(nidx + (size_t)(b*N_ + n) * K_);
    #pragma unroll
    for (int q4 = 0; q4 < K_/4; ++q4) {
        const int4 v = ip[q4];
        idx[q4*4+0] = v.x; idx[q4*4+1] = v.y; idx[q4*4+2] = v.z; idx[q4*4+3] = v.w;
    }
    const float* qb = query + (size_t)b*CQ_*N_ + (size_t)g*CQG_*N_;
    float lq[CQG_];
    #pragma unroll
    for (int c = 0; c < CQG_; ++c) lq[c] = qb[(size_t)c*N_ + n];
    float la[K_];
    #pragma unroll 4
    for (int k = 0; k < K_; ++k) {
        const float* qj = qb + idx[k];
        float s = 0.f;
        #pragma unroll
        for (int c = 0; c < CQG_; ++c) s = fmaf(lq[c], qj[(size_t)c*N_], s);
        la[k] = s;
    }
    float m = la[0];
    #pragma unroll
    for (int k = 1; k < K_; ++k) m = fmaxf(m, la[k]);
    float ssum = 0.f;
    #pragma unroll
    for (int k = 0; k < K_; ++k) { const float e = __expf(la[k] - m); la[k] = e; ssum += e; }
    const float inv = 1.f / ssum;
    #pragma unroll
    for (int k = 0; k < K_; ++k) la[k] *= inv;
    float* cb = cent + (size_t)bg * N_;
    #pragma unroll
    for (int k = 0; k < K_; ++k) atomicAdd(cb + idx[k], la[k]);
    float basec[CLPE_];
    #pragma unroll
    for (int c = 0; c < CLPE_; ++c) {
        const float4 a = sA[c];
        basec[c] = fmaf(a.x, cx, fmaf(a.y, cy, fmaf(a.z, cz, a.w)));
    }
    const float* vb = value + (size_t)b*CV_*N_ + (size_t)g*CVG_*N_;
    float accV[CVG_], accE[CLPE_];
    #pragma unroll
    for (int c = 0; c < CLPE_; ++c) { accV[c] = 0.f; accE[c] = 0.f; }
    float* fe = fenc + ((size_t)bg * CLPE_ * N_ + n) * K_;
    #pragma unroll 2
    for (int k = 0; k < K_; ++k) {
        const int j = idx[k];
        const float nx = xyz[(size_t)(b*N_ + j)*3 + 0];
        const float ny = xyz[(size_t)(b*N_ + j)*3 + 1];
        const float nz = xyz[(size_t)(b*N_ + j)*3 + 2];
        const float rx = cx - nx, ry = cy - ny, rz = cz - nz;
        const float d  = sqrtf(rx*rx + ry*ry + rz*rz);
        const float w  = la[k];
        const float* vj = vb + j;
        #pragma unroll
        for (int c = 0; c < CLPE_; ++c) {
            const float4 bb = sB[c];
            float e = basec[c];
            e = fmaf(bb.x, nx, e); e = fmaf(bb.y, ny, e);
            e = fmaf(bb.z, nz, e); e = fmaf(bb.w, d,  e);
            e = fmaxf(e, 0.f);
            fe[(size_t)c*(N_*K_) + k] = e;
            accE[c] = fmaf(w, e, accE[c]);
            accV[c] = fmaf(w, vj[(size_t)c*N_], accV[c]);
        }
    }
    float* ob = out + (size_t)bg * (CVG_ + CLPE_) * N_ + n;
    #pragma unroll
    for (int c = 0; c < CVG_; ++c)  ob[(size_t)c*N_]        = accV[c];
    #pragma unroll
    for (int c = 0; c < CLPE_; ++c) ob[(size_t)(CVG_+c)*N_] = accE[c];
}

extern "C" void kernel_launch(void* const* d_in, const int* in_sizes, int n_in,
                              void* d_out, int out_size, void* d_ws, size_t ws_size,
                              hipStream_t stream) {
    (void)in_sizes; (void)n_in; (void)out_size;

    const float* xyz   = (const float*)d_in[0];
    const float* query = (const float*)d_in[1];
    const float* value = (const float*)d_in[2];
    const int*   nidx  = (const int*)  d_in[3];
    const float* lpeW  = (const float*)d_in[5];
    const float* lpeB  = (const float*)d_in[6];
    const float* bnG   = (const float*)d_in[7];
    const float* bnB   = (const float*)d_in[8];
    const float* bnM   = (const float*)d_in[9];
    const float* bnV   = (const float*)d_in[10];

    float* out  = (float*)d_out;                                  // B*128*N
    float* fenc = out  + (size_t)B_ * (G_*(CVG_+CLPE_)) * N_;     // B*G*16*N*K
    float* cent = fenc + (size_t)B_ * G_ * CLPE_ * N_ * K_;       // B*G*N

    const size_t qv_bytes   = (size_t)NT_ * 64;                   // 33.5 MB
    const size_t xyz4_bytes = (size_t)B_ * N_ * sizeof(float4);   // 2 MB
    const size_t need = qv_bytes + xyz4_bytes;

    if (ws_size >= need) {
        uint4*  qvT  = (uint4*)d_ws;
        float4* xyz4 = (float4*)((char*)d_ws + qv_bytes);
        hipLaunchKernelGGL(gtl_prep, dim3(NT_/256), dim3(256), 0, stream,
                           query, value, xyz, qvT, xyz4, cent);
        hipLaunchKernelGGL(gtl_main, dim3(NT_/512), dim3(256), 0, stream,
                           qvT, xyz4, nidx, lpeW, lpeB, bnG, bnB, bnM, bnV,
                           out, fenc, cent);
    } else {
        (void)hipMemsetAsync(cent, 0, sizeof(float) * (size_t)B_ * G_ * N_, stream);
        hipLaunchKernelGGL(gtl_fallback, dim3(NT_/256), dim3(256), 0, stream,
                           xyz, query, value, nidx, lpeW, lpeB, bnG, bnB, bnM, bnV,
                           out, fenc, cent);
    }
}

// Round 6
// 994.770 us; speedup vs baseline: 1.2387x; 1.1423x over previous
//
#include <hip/hip_runtime.h>
#include <hip/hip_fp16.h>

#define B_    8
#define N_    16384
#define K_    16
#define G_    4
#define CQ_   64
#define CV_   64
#define CQG_  16
#define CVG_  16
#define CLPE_ 16
#define NT_   (B_*G_*N_)   // 524288 threads, one per (b,g,n)

typedef float f4v __attribute__((ext_vector_type(4)));
typedef int   i4v __attribute__((ext_vector_type(4)));

static __device__ __forceinline__ void nt_store4(float* p, float a, float b,
                                                 float c, float d) {
    f4v v = {a, b, c, d};
    __builtin_nontemporal_store(v, (f4v*)p);
}
static __device__ __forceinline__ void nt_store1(float* p, float a) {
    __builtin_nontemporal_store(a, p);
}

union QV { uint4 u; __half2 h[4]; };

// ---------------------------------------------------------------------------
// Kernel 1: transpose + fp16-pack (unchanged from R5).
// ---------------------------------------------------------------------------
__global__ __launch_bounds__(256) void gtl_prep(
    const float* __restrict__ query,
    const float* __restrict__ value,
    const float* __restrict__ xyz,
    uint4*  __restrict__ qvT,
    float4* __restrict__ xyz4,
    float*  __restrict__ cent)
{
    const int wid = blockIdx.x;          // 0..2047
    const int xcd = wid & 7;
    const int i   = wid >> 3;            // 0..255
    const int bg  = (xcd << 2) | (i >> 6);
    const int n   = ((i & 63) << 8) | threadIdx.x;
    const int g   = bg & (G_ - 1);
    const int b   = bg >> 2;
    const int gid = (bg << 14) | n;

    const float* qb = query + (size_t)b*CQ_*N_ + (size_t)g*CQG_*N_ + n;
    const float* vb = value + (size_t)b*CV_*N_ + (size_t)g*CVG_*N_ + n;

    uint u[16];
    #pragma unroll
    for (int q2 = 0; q2 < 8; ++q2) {
        const float a0 = qb[(size_t)(2*q2+0)*N_];
        const float a1 = qb[(size_t)(2*q2+1)*N_];
        const __half2 h = __floats2half2_rn(a0, a1);
        u[q2] = *(const uint*)&h;
    }
    #pragma unroll
    for (int q2 = 0; q2 < 8; ++q2) {
        const float a0 = vb[(size_t)(2*q2+0)*N_];
        const float a1 = vb[(size_t)(2*q2+1)*N_];
        const __half2 h = __floats2half2_rn(a0, a1);
        u[8+q2] = *(const uint*)&h;
    }

    uint4* o = qvT + (size_t)gid * 4;
    o[0] = make_uint4(u[0],  u[1],  u[2],  u[3]);   // q ch 0..7
    o[1] = make_uint4(u[4],  u[5],  u[6],  u[7]);   // q ch 8..15
    o[2] = make_uint4(u[8],  u[9],  u[10], u[11]);  // v ch 0..7
    o[3] = make_uint4(u[12], u[13], u[14], u[15]);  // v ch 8..15

    cent[gid] = 0.f;

    if (g == 0) {
        const size_t pp = (size_t)b*N_ + n;
        xyz4[pp] = make_float4(xyz[pp*3+0], xyz[pp*3+1], xyz[pp*3+2], 0.f);
    }
}

// ---------------------------------------------------------------------------
// Kernel 2: fused main pass, online softmax (R5 structure). NEW this round:
// fenc stores go through a per-wave LDS lane-exchange so each wave store
// instruction writes 1KB of CONTIGUOUS full lines (was: per-lane 16B chunks
// 64B apart -> partial-line NT writes -> ~2x HBM write amplification).
// Stride-17 LDS slots: write side 2 lanes/bank (free), read side <=4-way.
// Per-wave buffer + in-order per-wave DS ops -> no __syncthreads needed.
// ---------------------------------------------------------------------------
__global__ __launch_bounds__(256) void gtl_main(
    const uint4*  __restrict__ qvT,
    const float4* __restrict__ xyz4,
    const int*    __restrict__ nidx,
    const float*  __restrict__ lpeW,
    const float*  __restrict__ lpeB,
    const float*  __restrict__ bnG,
    const float*  __restrict__ bnB,
    const float*  __restrict__ bnM,
    const float*  __restrict__ bnV,
    float* __restrict__ out,
    float* __restrict__ fenc,
    float* __restrict__ cent)
{
    __shared__ float4 sA[CLPE_];          // scale*(center xyz coeffs), w = shift
    __shared__ float4 sB[CLPE_];          // scale*(neighbor xyz coeffs), w = scale*w0
    __shared__ float  sbuf[4][64*17];     // per-wave fenc staging (17.4KB)

    const int t    = threadIdx.x;
    const int w    = t >> 6;              // wave id 0..3
    const int lane = t & 63;

    if (t < CLPE_) {
        const float scale = bnG[t] * rsqrtf(bnV[t] + 1e-5f);
        const float shift = (lpeB[t] - bnM[t]) * scale + bnB[t];
        const float w0 = lpeW[t*10+0];
        const float w1 = lpeW[t*10+1], w2 = lpeW[t*10+2], w3 = lpeW[t*10+3];
        const float w4 = lpeW[t*10+4], w5 = lpeW[t*10+5], w6 = lpeW[t*10+6];
        const float w7 = lpeW[t*10+7], w8 = lpeW[t*10+8], w9 = lpeW[t*10+9];
        sA[t] = make_float4(scale*(w1+w4), scale*(w2+w5), scale*(w3+w6), shift);
        sB[t] = make_float4(scale*(w7-w1), scale*(w8-w2), scale*(w9-w3), scale*w0);
    }
    __syncthreads();

    const int wid  = blockIdx.x;    // 0..1023
    const int xcd  = wid & 7;
    const int half = wid >> 3;      // 0..127

    #pragma unroll 1
    for (int p = 0; p < 2; ++p) {
        const int slot = half + (p << 7);          // 0..255
        const int bg   = (xcd << 2) | (slot >> 6);
        const int n    = ((slot & 63) << 8) | t;
        const int b    = bg >> 2;
        const size_t xb = (size_t)b * N_;

        // neighbor indices (streamed once: non-temporal, keep out of L2)
        int idx[K_];
        {
            const i4v* ip = (const i4v*)(nidx + ((size_t)b*N_ + n) * K_);
            #pragma unroll
            for (int q4 = 0; q4 < K_/4; ++q4) {
                const i4v v = __builtin_nontemporal_load(ip + q4);
                idx[q4*4+0] = v.x; idx[q4*4+1] = v.y;
                idx[q4*4+2] = v.z; idx[q4*4+3] = v.w;
            }
        }

        const uint4* qvslab = qvT + (size_t)bg * N_ * 4;

        // center q -> f32 registers
        float lq[CQG_];
        {
            QV cA, cB;
            cA.u = qvslab[(size_t)n*4+0];
            cB.u = qvslab[(size_t)n*4+1];
            #pragma unroll
            for (int i2 = 0; i2 < 4; ++i2) {
                const float2 f = __half22float2(cA.h[i2]);
                lq[2*i2+0] = f.x; lq[2*i2+1] = f.y;
            }
            #pragma unroll
            for (int i2 = 0; i2 < 4; ++i2) {
                const float2 f = __half22float2(cB.h[i2]);
                lq[8+2*i2+0] = f.x; lq[8+2*i2+1] = f.y;
            }
        }
        const float4 cpt = xyz4[xb + n];

        // ---- fused gather + logits + online-softmax PV ----
        float la[K_];
        float accV[CVG_];
        __half2 nbh[2*K_];     // per k: (nx,ny),(nz,d) packed fp16
        #pragma unroll
        for (int c = 0; c < CVG_; ++c) accV[c] = 0.f;
        float m = -1e30f;

        #pragma unroll 4
        for (int k = 0; k < K_; ++k) {
            const int j = idx[k];
            const uint4* rp = qvslab + (size_t)j*4;   // one 64B line
            QV r0, r1, r2, r3;
            r0.u = rp[0]; r1.u = rp[1]; r2.u = rp[2]; r3.u = rp[3];
            const float4 pp = xyz4[xb + j];

            float s = 0.f;
            #pragma unroll
            for (int i2 = 0; i2 < 4; ++i2) {
                const float2 f = __half22float2(r0.h[i2]);
                s = fmaf(lq[2*i2+0], f.x, s);
                s = fmaf(lq[2*i2+1], f.y, s);
            }
            #pragma unroll
            for (int i2 = 0; i2 < 4; ++i2) {
                const float2 f = __half22float2(r1.h[i2]);
                s = fmaf(lq[8+2*i2+0], f.x, s);
                s = fmaf(lq[8+2*i2+1], f.y, s);
            }
            la[k] = s;

            const float mn = fmaxf(m, s);
            const float sc = __expf(m - mn);   // 0 on first k, 1 when max unchanged
            const float ww = __expf(s - mn);
            m = mn;

            #pragma unroll
            for (int i2 = 0; i2 < 4; ++i2) {
                const float2 f = __half22float2(r2.h[i2]);
                accV[2*i2+0] = fmaf(ww, f.x, accV[2*i2+0]*sc);
                accV[2*i2+1] = fmaf(ww, f.y, accV[2*i2+1]*sc);
            }
            #pragma unroll
            for (int i2 = 0; i2 < 4; ++i2) {
                const float2 f = __half22float2(r3.h[i2]);
                accV[8+2*i2+0] = fmaf(ww, f.x, accV[8+2*i2+0]*sc);
                accV[8+2*i2+1] = fmaf(ww, f.y, accV[8+2*i2+1]*sc);
            }

            const float rx = cpt.x - pp.x, ry = cpt.y - pp.y, rz = cpt.z - pp.z;
            const float d  = sqrtf(fmaf(rx,rx, fmaf(ry,ry, rz*rz)));
            nbh[2*k+0] = __floats2half2_rn(pp.x, pp.y);
            nbh[2*k+1] = __floats2half2_rn(pp.z, d);
        }

        // finish softmax: e_k = exp(s_k - m_final); accV already uses m_final
        float ssum = 0.f;
        #pragma unroll
        for (int k = 0; k < K_; ++k) {
            const float e = __expf(la[k] - m);
            la[k] = e; ssum += e;
        }
        const float inv = 1.f / ssum;
        #pragma unroll
        for (int k = 0; k < K_; ++k) la[k] *= inv;
        #pragma unroll
        for (int c = 0; c < CVG_; ++c) accV[c] *= inv;

        // centrality scatter-add (bg slab is XCD-local)
        {
            float* cb = cent + (size_t)bg * N_;
            #pragma unroll
            for (int k = 0; k < K_; ++k) atomicAdd(cb + idx[k], la[k]);
        }

        // k-invariant LPE base
        float basec[CLPE_];
        #pragma unroll
        for (int c = 0; c < CLPE_; ++c) {
            const float4 a = sA[c];
            basec[c] = fmaf(a.x, cpt.x, fmaf(a.y, cpt.y, fmaf(a.z, cpt.z, a.w)));
        }

        // ---- per-channel enc; fenc via LDS lane-exchange -> full-line NT ----
        // wave's 64 points start at n0 = n - lane; per (bg,c) fenc is
        // contiguous in n: region = fenc + ((bg*16+c)*N + n0)*16 floats (4KB).
        float* ob = out + (size_t)bg * (CVG_ + CLPE_) * N_ + n;
        const size_t n0 = (size_t)(n - lane);
        float* swb = &sbuf[w][0];

        #pragma unroll 2
        for (int c = 0; c < CLPE_; ++c) {
            const float4 wB = sB[c];
            const float base = basec[c];
            float e[K_];
            float acc = 0.f;
            #pragma unroll
            for (int k = 0; k < K_; ++k) {
                const float2 pxy = __half22float2(nbh[2*k+0]);
                const float2 pzd = __half22float2(nbh[2*k+1]);
                float tt = base;
                tt = fmaf(wB.x, pxy.x, tt);
                tt = fmaf(wB.y, pxy.y, tt);
                tt = fmaf(wB.z, pzd.x, tt);
                tt = fmaf(wB.w, pzd.y, tt);
                tt = fmaxf(tt, 0.f);
                e[k] = tt;
                acc  = fmaf(la[k], tt, acc);
            }

            // stage this lane's 16 values (stride-17 slot: conflict-free)
            float* sl = swb + lane*17;
            #pragma unroll
            for (int k = 0; k < K_; ++k) sl[k] = e[k];
            __builtin_amdgcn_wave_barrier();   // compiler fence; DS is in-order per wave

            // wave-coalesced full-line NT stores: instr i covers 1KB contiguous
            float* fc = fenc + (((size_t)bg*CLPE_ + c) * N_ + n0) * K_;
            #pragma unroll
            for (int i = 0; i < 4; ++i) {
                const int j  = i*64 + lane;        // chunk 0..255 (16B each)
                const int pt = j >> 2, q = j & 3;
                const float* rp = swb + pt*17 + q*4;
                nt_store4(fc + (size_t)j*4, rp[0], rp[1], rp[2], rp[3]);
            }
            __builtin_amdgcn_wave_barrier();   // order next c's writes after reads

            nt_store1(ob + (size_t)(CVG_ + c) * N_, acc);
        }

        #pragma unroll
        for (int c = 0; c < CVG_; ++c) nt_store1(ob + (size_t)c * N_, accV[c]);
    }
}

// ---------------------------------------------------------------------------
// Fallback (verified correct, fp32) if workspace is too small.
// ---------------------------------------------------------------------------
__global__ __launch_bounds__(256) void gtl_fallback(
    const float* __restrict__ xyz,
    const float* __restrict__ query,
    const float* __restrict__ value,
    const int*   __restrict__ nidx,
    const float* __restrict__ lpeW,
    const float* __restrict__ lpeB,
    const float* __restrict__ bnG,
    const float* __restrict__ bnB,
    const float* __restrict__ bnM,
    const float* __restrict__ bnV,
    float* __restrict__ out,
    float* __restrict__ fenc,
    float* __restrict__ cent)
{
    __shared__ float4 sA[CLPE_];
    __shared__ float4 sB[CLPE_];
    const int t = threadIdx.x;
    if (t < CLPE_) {
        const float scale = bnG[t] * rsqrtf(bnV[t] + 1e-5f);
        const float shift = (lpeB[t] - bnM[t]) * scale + bnB[t];
        const float w0 = lpeW[t*10+0];
        const float w1 = lpeW[t*10+1], w2 = lpeW[t*10+2], w3 = lpeW[t*10+3];
        const float w4 = lpeW[t*10+4], w5 = lpeW[t*10+5], w6 = lpeW[t*10+6];
        const float w7 = lpeW[t*10+7], w8 = lpeW[t*10+8], w9 = lpeW[t*10+9];
        sA[t] = make_float4(scale*(w1+w4), scale*(w2+w5), scale*(w3+w6), shift);
        sB[t] = make_float4(scale*(w7-w1), scale*(w8-w2), scale*(w9-w3), scale*w0);
    }
    __syncthreads();
    const int gid = blockIdx.x * 256 + t;
    const int n   = gid & (N_ - 1);
    const int bg  = gid >> 14;
    const int g   = bg & (G_ - 1);
    const int b   = bg >> 2;
    const float cx = xyz[(size_t)(b*N_ + n)*3 + 0];
    const float cy = xyz[(size_t)(b*N_ + n)*3 + 1];
    const float cz = xyz[(size_t)(b*N_ + n)*3 + 2];
    int idx[K_];
    const int4* ip = (const int4*)(nidx + (size_t)(b*N_ + n) * K_);
    #pragma unroll
    for (int q4 = 0; q4 < K_/4; ++q4) {
        const int4 v = ip[q4];
        idx[q4*4+0] = v.x; idx[q4*4+1] = v.y; idx[q4*4+2] = v.z; idx[q4*4+3] = v.w;
    }
    const float* qb = query + (size_t)b*CQ_*N_ + (size_t)g*CQG_*N_;
    float lq[CQG_];
    #pragma unroll
    for (int c = 0; c < CQG_; ++c) lq[c] = qb[(size_t)c*N_ + n];
    float la[K_];
    #pragma unroll 4
    for (int k = 0; k < K_; ++k) {
        const float* qj = qb + idx[k];
        float s = 0.f;
        #pragma unroll
        for (int c = 0; c < CQG_; ++c) s = fmaf(lq[c], qj[(size_t)c*N_], s);
        la[k] = s;
    }
    float m = la[0];
    #pragma unroll
    for (int k = 1; k < K_; ++k) m = fmaxf(m, la[k]);
    float ssum = 0.f;
    #pragma unroll
    for (int k = 0; k < K_; ++k) { const float e = __expf(la[k] - m); la[k] = e; ssum += e; }
    const float inv = 1.f / ssum;
    #pragma unroll
    for (int k = 0; k < K_; ++k) la[k] *= inv;
    float* cb = cent + (size_t)bg * N_;
    #pragma unroll
    for (int k = 0; k < K_; ++k) atomicAdd(cb + idx[k], la[k]);
    float basec[CLPE_];
    #pragma unroll
    for (int c = 0; c < CLPE_; ++c) {
        const float4 a = sA[c];
        basec[c] = fmaf(a.x, cx, fmaf(a.y, cy, fmaf(a.z, cz, a.w)));
    }
    const float* vb = value + (size_t)b*CV_*N_ + (size_t)g*CVG_*N_;
    float accV[CVG_], accE[CLPE_];
    #pragma unroll
    for (int c = 0; c < CLPE_; ++c) { accV[c] = 0.f; accE[c] = 0.f; }
    float* fe = fenc + ((size_t)bg * CLPE_ * N_ + n) * K_;
    #pragma unroll 2
    for (int k = 0; k < K_; ++k) {
        const int j = idx[k];
        const float nx = xyz[(size_t)(b*N_ + j)*3 + 0];
        const float ny = xyz[(size_t)(b*N_ + j)*3 + 1];
        const float nz = xyz[(size_t)(b*N_ + j)*3 + 2];
        const float rx = cx - nx, ry = cy - ny, rz = cz - nz;
        const float d  = sqrtf(rx*rx + ry*ry + rz*rz);
        const float w  = la[k];
        const float* vj = vb + j;
        #pragma unroll
        for (int c = 0; c < CLPE_; ++c) {
            const float4 bb = sB[c];
            float e = basec[c];
            e = fmaf(bb.x, nx, e); e = fmaf(bb.y, ny, e);
            e = fmaf(bb.z, nz, e); e = fmaf(bb.w, d,  e);
            e = fmaxf(e, 0.f);
            fe[(size_t)c*(N_*K_) + k] = e;
            accE[c] = fmaf(w, e, accE[c]);
            accV[c] = fmaf(w, vj[(size_t)c*N_], accV[c]);
        }
    }
    float* ob = out + (size_t)bg * (CVG_ + CLPE_) * N_ + n;
    #pragma unroll
    for (int c = 0; c < CVG_; ++c)  ob[(size_t)c*N_]        = accV[c];
    #pragma unroll
    for (int c = 0; c < CLPE_; ++c) ob[(size_t)(CVG_+c)*N_] = accE[c];
}

extern "C" void kernel_launch(void* const* d_in, const int* in_sizes, int n_in,
                              void* d_out, int out_size, void* d_ws, size_t ws_size,
                              hipStream_t stream) {
    (void)in_sizes; (void)n_in; (void)out_size;

    const float* xyz   = (const float*)d_in[0];
    const float* query = (const float*)d_in[1];
    const float* value = (const float*)d_in[2];
    const int*   nidx  = (const int*)  d_in[3];
    const float* lpeW  = (const float*)d_in[5];
    const float* lpeB  = (const float*)d_in[6];
    const float* bnG   = (const float*)d_in[7];
    const float* bnB   = (const float*)d_in[8];
    const float* bnM   = (const float*)d_in[9];
    const float* bnV   = (const float*)d_in[10];

    float* out  = (float*)d_out;                                  // B*128*N
    float* fenc = out  + (size_t)B_ * (G_*(CVG_+CLPE_)) * N_;     // B*G*16*N*K
    float* cent = fenc + (size_t)B_ * G_ * CLPE_ * N_ * K_;       // B*G*N

    const size_t qv_bytes   = (size_t)NT_ * 64;                   // 33.5 MB
    const size_t xyz4_bytes = (size_t)B_ * N_ * sizeof(float4);   // 2 MB
    const size_t need = qv_bytes + xyz4_bytes;

    if (ws_size >= need) {
        uint4*  qvT  = (uint4*)d_ws;
        float4* xyz4 = (float4*)((char*)d_ws + qv_bytes);
        hipLaunchKernelGGL(gtl_prep, dim3(NT_/256), dim3(256), 0, stream,
                           query, value, xyz, qvT, xyz4, cent);
        hipLaunchKernelGGL(gtl_main, dim3(NT_/512), dim3(256), 0, stream,
                           qvT, xyz4, nidx, lpeW, lpeB, bnG, bnB, bnM, bnV,
                           out, fenc, cent);
    } else {
        (void)hipMemsetAsync(cent, 0, sizeof(float) * (size_t)B_ * G_ * N_, stream);
        hipLaunchKernelGGL(gtl_fallback, dim3(NT_/256), dim3(256), 0, stream,
                           xyz, query, value, nidx, lpeW, lpeB, bnG, bnB, bnM, bnV,
                           out, fenc, cent);
    }
}

// Round 7
// 986.501 us; speedup vs baseline: 1.2491x; 1.0084x over previous
//
#include <hip/hip_runtime.h>
#include <hip/hip_fp16.h>

#define B_    8
#define N_    16384
#define K_    16
#define G_    4
#define CQ_   64
#define CV_   64
#define CQG_  16
#define CVG_  16
#define CLPE_ 16
#define NT_   (B_*G_*N_)   // 524288 threads, one per (b,g,n)

typedef float f4v __attribute__((ext_vector_type(4)));
typedef int   i4v __attribute__((ext_vector_type(4)));
typedef unsigned int u4v __attribute__((ext_vector_type(4)));

static __device__ __forceinline__ void nt_store4(float* p, float a, float b,
                                                 float c, float d) {
    f4v v = {a, b, c, d};
    __builtin_nontemporal_store(v, (f4v*)p);
}
static __device__ __forceinline__ void nt_store1(float* p, float a) {
    __builtin_nontemporal_store(a, p);
}

union QV { uint4 u; __half2 h[4]; };

// ---------------------------------------------------------------------------
// Kernel 1: transpose + fp16-pack. NEW this round: per-block LDS lane-exchange
// so qvT is written as contiguous full lines (1KB per wave store instruction).
// Previously each thread wrote its 64B record as 4x16B stores at 64B lane
// stride -> 64 partial-line transactions per wave instr (the same pathology
// fixed in gtl_main's fenc path in R6). Reads of query/value are non-temporal
// so the 67MB input stream doesn't evict the freshly written qvT slabs from
// the local (XCD-aligned) L2 before gtl_main consumes them.
// ---------------------------------------------------------------------------
__global__ __launch_bounds__(256) void gtl_prep(
    const float* __restrict__ query,
    const float* __restrict__ value,
    const float* __restrict__ xyz,
    uint4*  __restrict__ qvT,
    float4* __restrict__ xyz4,
    float*  __restrict__ cent)
{
    __shared__ unsigned int sbuf[256*17];   // 17.4KB staging, stride-17 slots

    const int t   = threadIdx.x;
    const int wid = blockIdx.x;          // 0..2047
    const int xcd = wid & 7;
    const int i   = wid >> 3;            // 0..255
    const int bg  = (xcd << 2) | (i >> 6);
    const int n0  = (i & 63) << 8;       // block's 256 consecutive points
    const int n   = n0 | t;
    const int g   = bg & (G_ - 1);
    const int b   = bg >> 2;
    const int gid = (bg << 14) | n;

    const float* qb = query + (size_t)b*CQ_*N_ + (size_t)g*CQG_*N_ + n;
    const float* vb = value + (size_t)b*CV_*N_ + (size_t)g*CVG_*N_ + n;

    // build this thread's 64B record in registers (nt loads: keep L2 clean)
    unsigned int u[16];
    #pragma unroll
    for (int q2 = 0; q2 < 8; ++q2) {
        const float a0 = __builtin_nontemporal_load(qb + (size_t)(2*q2+0)*N_);
        const float a1 = __builtin_nontemporal_load(qb + (size_t)(2*q2+1)*N_);
        const __half2 h = __floats2half2_rn(a0, a1);
        u[q2] = *(const unsigned int*)&h;
    }
    #pragma unroll
    for (int q2 = 0; q2 < 8; ++q2) {
        const float a0 = __builtin_nontemporal_load(vb + (size_t)(2*q2+0)*N_);
        const float a1 = __builtin_nontemporal_load(vb + (size_t)(2*q2+1)*N_);
        const __half2 h = __floats2half2_rn(a0, a1);
        u[8+q2] = *(const unsigned int*)&h;
    }

    // stage into stride-17 slot (2 lanes/bank on write side: free)
    #pragma unroll
    for (int k = 0; k < 16; ++k) sbuf[t*17 + k] = u[k];

    // cent zero + xyz pack while waiting
    cent[gid] = 0.f;
    if (g == 0) {
        const size_t pp = (size_t)b*N_ + n;
        xyz4[pp] = make_float4(xyz[pp*3+0], xyz[pp*3+1], xyz[pp*3+2], 0.f);
    }

    __syncthreads();

    // block's qvT region = 16KB contiguous; write chunk j = i2*256 + t
    // (16B each) -> every wave store instruction covers 1KB of full lines.
    uint4* ob = qvT + (size_t)(((size_t)bg << 14) | n0) * 4;
    #pragma unroll
    for (int i2 = 0; i2 < 4; ++i2) {
        const int j = i2*256 + t;          // chunk 0..1023
        const int r = j >> 2, q = j & 3;   // record r, uint4-part q
        const unsigned int* sp = &sbuf[r*17 + q*4];
        ob[j] = make_uint4(sp[0], sp[1], sp[2], sp[3]);
    }
}

// ---------------------------------------------------------------------------
// Kernel 2: fused main pass, online softmax (unchanged from R6).
// ---------------------------------------------------------------------------
__global__ __launch_bounds__(256) void gtl_main(
    const uint4*  __restrict__ qvT,
    const float4* __restrict__ xyz4,
    const int*    __restrict__ nidx,
    const float*  __restrict__ lpeW,
    const float*  __restrict__ lpeB,
    const float*  __restrict__ bnG,
    const float*  __restrict__ bnB,
    const float*  __restrict__ bnM,
    const float*  __restrict__ bnV,
    float* __restrict__ out,
    float* __restrict__ fenc,
    float* __restrict__ cent)
{
    __shared__ float4 sA[CLPE_];          // scale*(center xyz coeffs), w = shift
    __shared__ float4 sB[CLPE_];          // scale*(neighbor xyz coeffs), w = scale*w0
    __shared__ float  sbuf[4][64*17];     // per-wave fenc staging (17.4KB)

    const int t    = threadIdx.x;
    const int w    = t >> 6;              // wave id 0..3
    const int lane = t & 63;

    if (t < CLPE_) {
        const float scale = bnG[t] * rsqrtf(bnV[t] + 1e-5f);
        const float shift = (lpeB[t] - bnM[t]) * scale + bnB[t];
        const float w0 = lpeW[t*10+0];
        const float w1 = lpeW[t*10+1], w2 = lpeW[t*10+2], w3 = lpeW[t*10+3];
        const float w4 = lpeW[t*10+4], w5 = lpeW[t*10+5], w6 = lpeW[t*10+6];
        const float w7 = lpeW[t*10+7], w8 = lpeW[t*10+8], w9 = lpeW[t*10+9];
        sA[t] = make_float4(scale*(w1+w4), scale*(w2+w5), scale*(w3+w6), shift);
        sB[t] = make_float4(scale*(w7-w1), scale*(w8-w2), scale*(w9-w3), scale*w0);
    }
    __syncthreads();

    const int wid  = blockIdx.x;    // 0..1023
    const int xcd  = wid & 7;
    const int half = wid >> 3;      // 0..127

    #pragma unroll 1
    for (int p = 0; p < 2; ++p) {
        const int slot = half + (p << 7);          // 0..255
        const int bg   = (xcd << 2) | (slot >> 6);
        const int n    = ((slot & 63) << 8) | t;
        const int b    = bg >> 2;
        const size_t xb = (size_t)b * N_;

        // neighbor indices (streamed once: non-temporal, keep out of L2)
        int idx[K_];
        {
            const i4v* ip = (const i4v*)(nidx + ((size_t)b*N_ + n) * K_);
            #pragma unroll
            for (int q4 = 0; q4 < K_/4; ++q4) {
                const i4v v = __builtin_nontemporal_load(ip + q4);
                idx[q4*4+0] = v.x; idx[q4*4+1] = v.y;
                idx[q4*4+2] = v.z; idx[q4*4+3] = v.w;
            }
        }

        const uint4* qvslab = qvT + (size_t)bg * N_ * 4;

        // center q -> f32 registers
        float lq[CQG_];
        {
            QV cA, cB;
            cA.u = qvslab[(size_t)n*4+0];
            cB.u = qvslab[(size_t)n*4+1];
            #pragma unroll
            for (int i2 = 0; i2 < 4; ++i2) {
                const float2 f = __half22float2(cA.h[i2]);
                lq[2*i2+0] = f.x; lq[2*i2+1] = f.y;
            }
            #pragma unroll
            for (int i2 = 0; i2 < 4; ++i2) {
                const float2 f = __half22float2(cB.h[i2]);
                lq[8+2*i2+0] = f.x; lq[8+2*i2+1] = f.y;
            }
        }
        const float4 cpt = xyz4[xb + n];

        // ---- fused gather + logits + online-softmax PV ----
        float la[K_];
        float accV[CVG_];
        __half2 nbh[2*K_];     // per k: (nx,ny),(nz,d) packed fp16
        #pragma unroll
        for (int c = 0; c < CVG_; ++c) accV[c] = 0.f;
        float m = -1e30f;

        #pragma unroll 4
        for (int k = 0; k < K_; ++k) {
            const int j = idx[k];
            const uint4* rp = qvslab + (size_t)j*4;   // one 64B line
            QV r0, r1, r2, r3;
            r0.u = rp[0]; r1.u = rp[1]; r2.u = rp[2]; r3.u = rp[3];
            const float4 pp = xyz4[xb + j];

            float s = 0.f;
            #pragma unroll
            for (int i2 = 0; i2 < 4; ++i2) {
                const float2 f = __half22float2(r0.h[i2]);
                s = fmaf(lq[2*i2+0], f.x, s);
                s = fmaf(lq[2*i2+1], f.y, s);
            }
            #pragma unroll
            for (int i2 = 0; i2 < 4; ++i2) {
                const float2 f = __half22float2(r1.h[i2]);
                s = fmaf(lq[8+2*i2+0], f.x, s);
                s = fmaf(lq[8+2*i2+1], f.y, s);
            }
            la[k] = s;

            const float mn = fmaxf(m, s);
            const float sc = __expf(m - mn);   // 0 on first k, 1 when max unchanged
            const float ww = __expf(s - mn);
            m = mn;

            #pragma unroll
            for (int i2 = 0; i2 < 4; ++i2) {
                const float2 f = __half22float2(r2.h[i2]);
                accV[2*i2+0] = fmaf(ww, f.x, accV[2*i2+0]*sc);
                accV[2*i2+1] = fmaf(ww, f.y, accV[2*i2+1]*sc);
            }
            #pragma unroll
            for (int i2 = 0; i2 < 4; ++i2) {
                const float2 f = __half22float2(r3.h[i2]);
                accV[8+2*i2+0] = fmaf(ww, f.x, accV[8+2*i2+0]*sc);
                accV[8+2*i2+1] = fmaf(ww, f.y, accV[8+2*i2+1]*sc);
            }

            const float rx = cpt.x - pp.x, ry = cpt.y - pp.y, rz = cpt.z - pp.z;
            const float d  = sqrtf(fmaf(rx,rx, fmaf(ry,ry, rz*rz)));
            nbh[2*k+0] = __floats2half2_rn(pp.x, pp.y);
            nbh[2*k+1] = __floats2half2_rn(pp.z, d);
        }

        // finish softmax: e_k = exp(s_k - m_final); accV already uses m_final
        float ssum = 0.f;
        #pragma unroll
        for (int k = 0; k < K_; ++k) {
            const float e = __expf(la[k] - m);
            la[k] = e; ssum += e;
        }
        const float inv = 1.f / ssum;
        #pragma unroll
        for (int k = 0; k < K_; ++k) la[k] *= inv;
        #pragma unroll
        for (int c = 0; c < CVG_; ++c) accV[c] *= inv;

        // centrality scatter-add (bg slab is XCD-local)
        {
            float* cb = cent + (size_t)bg * N_;
            #pragma unroll
            for (int k = 0; k < K_; ++k) atomicAdd(cb + idx[k], la[k]);
        }

        // k-invariant LPE base
        float basec[CLPE_];
        #pragma unroll
        for (int c = 0; c < CLPE_; ++c) {
            const float4 a = sA[c];
            basec[c] = fmaf(a.x, cpt.x, fmaf(a.y, cpt.y, fmaf(a.z, cpt.z, a.w)));
        }

        // ---- per-channel enc; fenc via LDS lane-exchange -> full-line NT ----
        float* ob = out + (size_t)bg * (CVG_ + CLPE_) * N_ + n;
        const size_t n0 = (size_t)(n - lane);
        float* swb = &sbuf[w][0];

        #pragma unroll 2
        for (int c = 0; c < CLPE_; ++c) {
            const float4 wB = sB[c];
            const float base = basec[c];
            float e[K_];
            float acc = 0.f;
            #pragma unroll
            for (int k = 0; k < K_; ++k) {
                const float2 pxy = __half22float2(nbh[2*k+0]);
                const float2 pzd = __half22float2(nbh[2*k+1]);
                float tt = base;
                tt = fmaf(wB.x, pxy.x, tt);
                tt = fmaf(wB.y, pxy.y, tt);
                tt = fmaf(wB.z, pzd.x, tt);
                tt = fmaf(wB.w, pzd.y, tt);
                tt = fmaxf(tt, 0.f);
                e[k] = tt;
                acc  = fmaf(la[k], tt, acc);
            }

            // stage this lane's 16 values (stride-17 slot: conflict-free)
            float* sl = swb + lane*17;
            #pragma unroll
            for (int k = 0; k < K_; ++k) sl[k] = e[k];
            __builtin_amdgcn_wave_barrier();   // compiler fence; DS in-order per wave

            // wave-coalesced full-line NT stores: instr i covers 1KB contiguous
            float* fc = fenc + (((size_t)bg*CLPE_ + c) * N_ + n0) * K_;
            #pragma unroll
            for (int i = 0; i < 4; ++i) {
                const int j  = i*64 + lane;        // chunk 0..255 (16B each)
                const int pt = j >> 2, q = j & 3;
                const float* rp = swb + pt*17 + q*4;
                nt_store4(fc + (size_t)j*4, rp[0], rp[1], rp[2], rp[3]);
            }
            __builtin_amdgcn_wave_barrier();   // order next c's writes after reads

            nt_store1(ob + (size_t)(CVG_ + c) * N_, acc);
        }

        #pragma unroll
        for (int c = 0; c < CVG_; ++c) nt_store1(ob + (size_t)c * N_, accV[c]);
    }
}

// ---------------------------------------------------------------------------
// Fallback (verified correct, fp32) if workspace is too small.
// ---------------------------------------------------------------------------
__global__ __launch_bounds__(256) void gtl_fallback(
    const float* __restrict__ xyz,
    const float* __restrict__ query,
    const float* __restrict__ value,
    const int*   __restrict__ nidx,
    const float* __restrict__ lpeW,
    const float* __restrict__ lpeB,
    const float* __restrict__ bnG,
    const float* __restrict__ bnB,
    const float* __restrict__ bnM,
    const float* __restrict__ bnV,
    float* __restrict__ out,
    float* __restrict__ fenc,
    float* __restrict__ cent)
{
    __shared__ float4 sA[CLPE_];
    __shared__ float4 sB[CLPE_];
    const int t = threadIdx.x;
    if (t < CLPE_) {
        const float scale = bnG[t] * rsqrtf(bnV[t] + 1e-5f);
        const float shift = (lpeB[t] - bnM[t]) * scale + bnB[t];
        const float w0 = lpeW[t*10+0];
        const float w1 = lpeW[t*10+1], w2 = lpeW[t*10+2], w3 = lpeW[t*10+3];
        const float w4 = lpeW[t*10+4], w5 = lpeW[t*10+5], w6 = lpeW[t*10+6];
        const float w7 = lpeW[t*10+7], w8 = lpeW[t*10+8], w9 = lpeW[t*10+9];
        sA[t] = make_float4(scale*(w1+w4), scale*(w2+w5), scale*(w3+w6), shift);
        sB[t] = make_float4(scale*(w7-w1), scale*(w8-w2), scale*(w9-w3), scale*w0);
    }
    __syncthreads();
    const int gid = blockIdx.x * 256 + t;
    const int n   = gid & (N_ - 1);
    const int bg  = gid >> 14;
    const int g   = bg & (G_ - 1);
    const int b   = bg >> 2;
    const float cx = xyz[(size_t)(b*N_ + n)*3 + 0];
    const float cy = xyz[(size_t)(b*N_ + n)*3 + 1];
    const float cz = xyz[(size_t)(b*N_ + n)*3 + 2];
    int idx[K_];
    const int4* ip = (const int4*)(nidx + (size_t)(b*N_ + n) * K_);
    #pragma unroll
    for (int q4 = 0; q4 < K_/4; ++q4) {
        const int4 v = ip[q4];
        idx[q4*4+0] = v.x; idx[q4*4+1] = v.y; idx[q4*4+2] = v.z; idx[q4*4+3] = v.w;
    }
    const float* qb = query + (size_t)b*CQ_*N_ + (size_t)g*CQG_*N_;
    float lq[CQG_];
    #pragma unroll
    for (int c = 0; c < CQG_; ++c) lq[c] = qb[(size_t)c*N_ + n];
    float la[K_];
    #pragma unroll 4
    for (int k = 0; k < K_; ++k) {
        const float* qj = qb + idx[k];
        float s = 0.f;
        #pragma unroll
        for (int c = 0; c < CQG_; ++c) s = fmaf(lq[c], qj[(size_t)c*N_], s);
        la[k] = s;
    }
    float m = la[0];
    #pragma unroll
    for (int k = 1; k < K_; ++k) m = fmaxf(m, la[k]);
    float ssum = 0.f;
    #pragma unroll
    for (int k = 0; k < K_; ++k) { const float e = __expf(la[k] - m); la[k] = e; ssum += e; }
    const float inv = 1.f / ssum;
    #pragma unroll
    for (int k = 0; k < K_; ++k) la[k] *= inv;
    float* cb = cent + (size_t)bg * N_;
    #pragma unroll
    for (int k = 0; k < K_; ++k) atomicAdd(cb + idx[k], la[k]);
    float basec[CLPE_];
    #pragma unroll
    for (int c = 0; c < CLPE_; ++c) {
        const float4 a = sA[c];
        basec[c] = fmaf(a.x, cx, fmaf(a.y, cy, fmaf(a.z, cz, a.w)));
    }
    const float* vb = value + (size_t)b*CV_*N_ + (size_t)g*CVG_*N_;
    float accV[CVG_], accE[CLPE_];
    #pragma unroll
    for (int c = 0; c < CLPE_; ++c) { accV[c] = 0.f; accE[c] = 0.f; }
    float* fe = fenc + ((size_t)bg * CLPE_ * N_ + n) * K_;
    #pragma unroll 2
    for (int k = 0; k < K_; ++k) {
        const int j = idx[k];
        const float nx = xyz[(size_t)(b*N_ + j)*3 + 0];
        const float ny = xyz[(size_t)(b*N_ + j)*3 + 1];
        const float nz = xyz[(size_t)(b*N_ + j)*3 + 2];
        const float rx = cx - nx, ry = cy - ny, rz = cz - nz;
        const float d  = sqrtf(rx*rx + ry*ry + rz*rz);
        const float w  = la[k];
        const float* vj = vb + j;
        #pragma unroll
        for (int c = 0; c < CLPE_; ++c) {
            const float4 bb = sB[c];
            float e = basec[c];
            e = fmaf(bb.x, nx, e); e = fmaf(bb.y, ny, e);
            e = fmaf(bb.z, nz, e); e = fmaf(bb.w, d,  e);
            e = fmaxf(e, 0.f);
            fe[(size_t)c*(N_*K_) + k] = e;
            accE[c] = fmaf(w, e, accE[c]);
            accV[c] = fmaf(w, vj[(size_t)c*N_], accV[c]);
        }
    }
    float* ob = out + (size_t)bg * (CVG_ + CLPE_) * N_ + n;
    #pragma unroll
    for (int c = 0; c < CVG_; ++c)  ob[(size_t)c*N_]        = accV[c];
    #pragma unroll
    for (int c = 0; c < CLPE_; ++c) ob[(size_t)(CVG_+c)*N_] = accE[c];
}

extern "C" void kernel_launch(void* const* d_in, const int* in_sizes, int n_in,
                              void* d_out, int out_size, void* d_ws, size_t ws_size,
                              hipStream_t stream) {
    (void)in_sizes; (void)n_in; (void)out_size;

    const float* xyz   = (const float*)d_in[0];
    const float* query = (const float*)d_in[1];
    const float* value = (const float*)d_in[2];
    const int*   nidx  = (const int*)  d_in[3];
    const float* lpeW  = (const float*)d_in[5];
    const float* lpeB  = (const float*)d_in[6];
    const float* bnG   = (const float*)d_in[7];
    const float* bnB   = (const float*)d_in[8];
    const float* bnM   = (const float*)d_in[9];
    const float* bnV   = (const float*)d_in[10];

    float* out  = (float*)d_out;                                  // B*128*N
    float* fenc = out  + (size_t)B_ * (G_*(CVG_+CLPE_)) * N_;     // B*G*16*N*K
    float* cent = fenc + (size_t)B_ * G_ * CLPE_ * N_ * K_;       // B*G*N

    const size_t qv_bytes   = (size_t)NT_ * 64;                   // 33.5 MB
    const size_t xyz4_bytes = (size_t)B_ * N_ * sizeof(float4);   // 2 MB
    const size_t need = qv_bytes + xyz4_bytes;

    if (ws_size >= need) {
        uint4*  qvT  = (uint4*)d_ws;
        float4* xyz4 = (float4*)((char*)d_ws + qv_bytes);
        hipLaunchKernelGGL(gtl_prep, dim3(NT_/256), dim3(256), 0, stream,
                           query, value, xyz, qvT, xyz4, cent);
        hipLaunchKernelGGL(gtl_main, dim3(NT_/512), dim3(256), 0, stream,
                           qvT, xyz4, nidx, lpeW, lpeB, bnG, bnB, bnM, bnV,
                           out, fenc, cent);
    } else {
        (void)hipMemsetAsync(cent, 0, sizeof(float) * (size_t)B_ * G_ * N_, stream);
        hipLaunchKernelGGL(gtl_fallback, dim3(NT_/256), dim3(256), 0, stream,
                           xyz, query, value, nidx, lpeW, lpeB, bnG, bnB, bnM, bnV,
                           out, fenc, cent);
    }
}